// Round 11
// baseline (3429.215 us; speedup 1.0000x reference)
//
#include <hip/hip_runtime.h>
#include <math.h>

typedef __bf16 bf16_t;
typedef __bf16 bf16x4 __attribute__((ext_vector_type(4)));
typedef __bf16 bf16x8 __attribute__((ext_vector_type(8)));
typedef float f32x4 __attribute__((ext_vector_type(4)));
typedef unsigned long long u64;

#define MFMA_16x16x32(A, B, C) __builtin_amdgcn_mfma_f32_16x16x32_bf16((A), (B), (C), 0, 0, 0)

static constexpr int Bn = 64;    // batch
static constexpr int Tn = 512;   // time
static constexpr int Dn = 1024;  // input dim
static constexpr int Hn = 2048;  // hidden
static constexpr int Cn = 5;     // classes
static constexpr int NGB = 64;   // blocks per batch-group
static constexpr int NGRP = 4;   // batch groups (16 rows each)
static constexpr int NBT = NGB * NGRP;  // 256 blocks = full GPU
static constexpr int NW = 16;    // waves per block (1024 threads)

// LDS swizzle for the xw GEMM tiles (32 bf16 = 64B rows)
#define SWZ64(row, kb)  ((((row) * 64) + (kb)) ^ (((row) & 3) << 4))

// ---------------- conversion kernels ----------------
__global__ __launch_bounds__(256) void cvt_bf16_k(const float* __restrict__ in,
                                                  bf16_t* __restrict__ out, int n4) {
  int i = blockIdx.x * 256 + threadIdx.x;
  if (i >= n4) return;
  float4 v = reinterpret_cast<const float4*>(in)[i];
  bf16x4 o;
  o[0] = (bf16_t)v.x; o[1] = (bf16_t)v.y; o[2] = (bf16_t)v.z; o[3] = (bf16_t)v.w;
  reinterpret_cast<bf16x4*>(out)[i] = o;
}

__global__ __launch_bounds__(256) void cvt_hilo_k(const float* __restrict__ in,
                                                  bf16_t* __restrict__ hi,
                                                  bf16_t* __restrict__ lo, int n4) {
  int i = blockIdx.x * 256 + threadIdx.x;
  if (i >= n4) return;
  float4 v = reinterpret_cast<const float4*>(in)[i];
  float f[4] = {v.x, v.y, v.z, v.w};
  bf16x4 h, l;
#pragma unroll
  for (int j = 0; j < 4; ++j) {
    bf16_t hb = (bf16_t)f[j];
    h[j] = hb;
    l[j] = (bf16_t)(f[j] - (float)hb);
  }
  reinterpret_cast<bf16x4*>(hi)[i] = h;
  reinterpret_cast<bf16x4*>(lo)[i] = l;
}

// ---------------- xw projection GEMM ----------------
__global__ __launch_bounds__(256) void gemm_xw_k(const float* __restrict__ A,
                                                 const bf16_t* __restrict__ Bw,
                                                 const float* __restrict__ bias,
                                                 bf16_t* __restrict__ C) {
  constexpr int K = Dn;
  constexpr int N = Hn;
  constexpr int NT = K / 32;
  __shared__ char As[2][128 * 64];
  __shared__ char Bs[2][128 * 64];

  const int tid = threadIdx.x;
  const int lane = tid & 63;
  const int wv = tid >> 6;
  const int wm = (wv >> 1) * 64;
  const int wn = (wv & 1) * 64;
  const int cl = lane & 15;
  const int kh = lane >> 4;
  const long m0 = (long)blockIdx.y * 128;
  const long n0 = (long)blockIdx.x * 128;

  const int srow = tid >> 1;
  const int scolb = (tid & 1) * 32;

  f32x4 acc[4][4] = {};
  float4 pa[4];
  uint4 pb[2];

  auto issue = [&](int kt) {
    const float* ap = A + (m0 + srow) * K + kt * 32 + (tid & 1) * 16;
#pragma unroll
    for (int i = 0; i < 4; ++i) pa[i] = reinterpret_cast<const float4*>(ap)[i];
    const bf16_t* bp = Bw + (n0 + srow) * K + kt * 32 + (tid & 1) * 16;
    pb[0] = reinterpret_cast<const uint4*>(bp)[0];
    pb[1] = reinterpret_cast<const uint4*>(bp)[1];
  };
  auto commit = [&](int buf) {
    bf16x8 a0, a1;
    a0[0] = (bf16_t)pa[0].x; a0[1] = (bf16_t)pa[0].y; a0[2] = (bf16_t)pa[0].z; a0[3] = (bf16_t)pa[0].w;
    a0[4] = (bf16_t)pa[1].x; a0[5] = (bf16_t)pa[1].y; a0[6] = (bf16_t)pa[1].z; a0[7] = (bf16_t)pa[1].w;
    a1[0] = (bf16_t)pa[2].x; a1[1] = (bf16_t)pa[2].y; a1[2] = (bf16_t)pa[2].z; a1[3] = (bf16_t)pa[2].w;
    a1[4] = (bf16_t)pa[3].x; a1[5] = (bf16_t)pa[3].y; a1[6] = (bf16_t)pa[3].z; a1[7] = (bf16_t)pa[3].w;
    *reinterpret_cast<bf16x8*>(&As[buf][SWZ64(srow, scolb)]) = a0;
    *reinterpret_cast<bf16x8*>(&As[buf][SWZ64(srow, scolb + 16)]) = a1;
    *reinterpret_cast<uint4*>(&Bs[buf][SWZ64(srow, scolb)]) = pb[0];
    *reinterpret_cast<uint4*>(&Bs[buf][SWZ64(srow, scolb + 16)]) = pb[1];
  };

  issue(0);
  commit(0);
  for (int kt = 0; kt < NT; ++kt) {
    const int buf = kt & 1;
    __syncthreads();
    if (kt + 1 < NT) issue(kt + 1);
    bf16x8 af[4], bfr[4];
#pragma unroll
    for (int i = 0; i < 4; ++i)
      af[i] = *reinterpret_cast<const bf16x8*>(&As[buf][SWZ64(wm + i * 16 + cl, kh * 16)]);
#pragma unroll
    for (int j = 0; j < 4; ++j)
      bfr[j] = *reinterpret_cast<const bf16x8*>(&Bs[buf][SWZ64(wn + j * 16 + cl, kh * 16)]);
#pragma unroll
    for (int i = 0; i < 4; ++i)
#pragma unroll
      for (int j = 0; j < 4; ++j)
        acc[i][j] = MFMA_16x16x32(af[i], bfr[j], acc[i][j]);
    if (kt + 1 < NT) commit((kt + 1) & 1);
  }

  const int rl4 = kh * 4;
#pragma unroll
  for (int j = 0; j < 4; ++j) {
    const long gcol = n0 + wn + j * 16 + cl;
    const float bv = bias[gcol];
#pragma unroll
    for (int i = 0; i < 4; ++i) {
      const long grow = m0 + wm + i * 16 + rl4;
#pragma unroll
      for (int q = 0; q < 4; ++q)
        C[(grow + q) * N + gcol] = (bf16_t)(acc[i][j][q] + bv);
    }
  }
}

// ---------------- persistent scan kernel ----------------
// Round-11: PER-CONSUMER MAILBOX DATAFLOW on top of r10's geometry.
//   Geometry (r10): 256 blocks x 1024 threads; 4 groups x 16 batch rows;
//   64 blocks/group x 32 cols; 16 waves = 16 k-splits x 128 K; U in VGPRs;
//   LDS = double-buffered red only; groups on XCD pairs (bid%8 heuristic).
//   Sync (new): no wave0 relay, no post-poll sync. Each consumer wave (j,wv)
//   needs cols wv*128..+127 of h -> exactly 8 producer flags, laid out
//   CONTIGUOUSLY in a private 32B mailbox mb[g][j][wv][8]. Producer storer
//   wave (j',sw), after its wave-local vmcnt(0) drain, broadcasts t+1 to the
//   64 consumer mailboxes with ONE 64-lane scattered store (lane l -> block
//   l, wave j'>>2, slot (j'&3)*2+sw). Consumers self-gate at loop top.
//   This removes the wave0-relay MALL RT, one __syncthreads, and the
//   max-over-64 jitter (each wave waits only on its 8 producers).
//   Designed around the r7/r8 flood modes: each mailbox line is read by
//   <=4 waves of one block (private), and flags arrive 8-per-32B dense.
//   1 __syncthreads/step (red WAR safe: a wave rewrites red[p] only after
//   syncB_{t+1}, which storers reach only after finishing red[p] reads).
// Coherence (r3): h stores sc0sc1 -> MALL; h loads plain cached on virgin
// rotated slots (no fence). Fallback rot=0: ping-pong + acquire fence.
__global__ __launch_bounds__(1024, 1) void scan_k(
    const bf16_t* __restrict__ Uhi, const bf16_t* __restrict__ Ulo,
    const float* __restrict__ Ub, const bf16_t* __restrict__ XW,
    bf16_t* __restrict__ Hc, long Hstep, int rot,
    const bf16_t* __restrict__ V1w, const float* __restrict__ V1b,
    float* __restrict__ Z1,
    const float* __restrict__ V2w, const float* __restrict__ V2b,
    float* __restrict__ out, unsigned* __restrict__ slots) {
  extern __shared__ char smem[];
  float* redb = (float*)smem;  // red[2][16][512] f32 = 64 KB

  const int tid = threadIdx.x;
  const int lane = tid & 63;
  const int wv = tid >> 6;             // 0..15 = k-split (128 K each)
  const int cl = lane & 15;
  const int kh = lane >> 4;
  const int bid = blockIdx.x;
  // XCD-pair group mapping (assumes bid%8 = XCD round-robin; perf-only)
  const int g = (bid & 7) >> 1;              // group 0..3
  const int j = (bid >> 3) * 2 + (bid & 1);  // group-local block 0..63
  const int n0 = j * 32;               // owned 32 columns
  const int row0 = g * 16;             // group's 16 batch rows
  // mailboxes: mb[g][block][wave][8 flags] u32, 32B per (block,wave)
  unsigned* mb = slots + (size_t)g * (NGB * NW * 8);
  // consumer gate address: my mailbox, lanes duplicate over the 8 slots
  const int moff_cons = (j * NW + wv) * 8 + (lane & 7);

  // ---- U fragments direct from global (one-time; loop-invariant) ----
  bf16x8 Ubh[2][4], Ubl[2][4];  // [col-tile][ksub] = 64 VGPRs
#pragma unroll
  for (int ct = 0; ct < 2; ++ct)
#pragma unroll
    for (int ksub = 0; ksub < 4; ++ksub) {
      const long uoff = (long)(n0 + ct * 16 + cl) * Hn + wv * 128 + ksub * 32 + kh * 8;
      Ubh[ct][ksub] = *reinterpret_cast<const bf16x8*>(Uhi + uoff);
      Ubl[ct][ksub] = *reinterpret_cast<const bf16x8*>(Ulo + uoff);
    }

  // storer waves: wv 0,1 each own 8 rows x 32 cols (4 outputs/lane)
  const bool storer = (wv < 2);
  const int srow = (wv & 1) * 8 + (lane >> 3);   // 0..15
  const int scol = (lane & 7) * 4;               // col group of 4
  // producer broadcast address: lane l -> block l's mailbox, wave j>>2,
  // slot (j&3)*2 + sw   (sw == wv for the two storer waves)
  const int moff_prod = (lane * NW + (j >> 2)) * 8 + (j & 3) * 2 + wv;

  float4 bv4 = {0.f, 0.f, 0.f, 0.f};
  if (storer) bv4 = *reinterpret_cast<const float4*>(Ub + n0 + scol);
  const long xw_off = (long)(row0 + srow) * (Tn * Hn) + n0 + scol;

  bf16x4 ad = {};
  if (storer) ad = *reinterpret_cast<const bf16x4*>(XW + xw_off);

  bf16_t* hin = Hc;            // slot 0 = zeros
  bf16_t* hout = Hc + Hstep;   // slot 1

  for (int t = 0; t < Tn; ++t) {
    // ---- per-wave self-gate: my 8 producers have published h_t ----
    {
      const unsigned tgt = (unsigned)t;  // t=0: mailboxes memset 0 -> passes
      for (;;) {
        unsigned v = __hip_atomic_load(mb + moff_cons, __ATOMIC_RELAXED,
                                       __HIP_MEMORY_SCOPE_AGENT);
        if (__all((int)(v >= tgt))) break;
      }
      asm volatile("" ::: "memory");  // don't hoist h loads above the gate
      if (!rot) __builtin_amdgcn_fence(__ATOMIC_ACQUIRE, "agent");
    }

    const bf16_t* arow = hin + (long)(row0 + cl) * Hn + wv * 128 + kh * 8;

    bf16x8 a[4];
#pragma unroll
    for (int ksub = 0; ksub < 4; ++ksub)
      a[ksub] = *reinterpret_cast<const bf16x8*>(arow + ksub * 32);

    f32x4 acch[2] = {}, accl[2] = {};
#pragma unroll
    for (int ksub = 0; ksub < 4; ++ksub) {
      acch[0] = MFMA_16x16x32(a[ksub], Ubh[0][ksub], acch[0]);
      accl[0] = MFMA_16x16x32(a[ksub], Ubl[0][ksub], accl[0]);
      acch[1] = MFMA_16x16x32(a[ksub], Ubh[1][ksub], acch[1]);
      accl[1] = MFMA_16x16x32(a[ksub], Ubl[1][ksub], accl[1]);
    }

    // k-split partials -> red[t&1] (double-buffered)
    float* red = redb + (t & 1) * 8192;
#pragma unroll
    for (int ct = 0; ct < 2; ++ct)
#pragma unroll
      for (int q = 0; q < 4; ++q)
        red[wv * 512 + (kh * 4 + q) * 32 + ct * 16 + cl] = acch[ct][q] + accl[ct][q];

    __syncthreads();  // the ONLY block sync per step

    // storer waves: combine 16 k-splits (contiguous float4 reads),
    // bias+xw+relu, one u64 sc0sc1 store, WAVE-LOCAL drain, mailbox bcast.
    if (storer) {
      const int ri = srow * 32 + scol;
      float4 s = {0.f, 0.f, 0.f, 0.f};
#pragma unroll
      for (int w = 0; w < NW; ++w) {
        float4 p = *reinterpret_cast<const float4*>(&red[w * 512 + ri]);
        s.x += p.x; s.y += p.y; s.z += p.z; s.w += p.w;
      }
      bf16x4 hv;
      hv[0] = (bf16_t)fmaxf(s.x + bv4.x + (float)ad[0], 0.f);
      hv[1] = (bf16_t)fmaxf(s.y + bv4.y + (float)ad[1], 0.f);
      hv[2] = (bf16_t)fmaxf(s.z + bv4.z + (float)ad[2], 0.f);
      hv[3] = (bf16_t)fmaxf(s.w + bv4.w + (float)ad[3], 0.f);
      __hip_atomic_store(
          reinterpret_cast<u64*>(hout + (long)(row0 + srow) * Hn + n0 + scol),
          *reinterpret_cast<const u64*>(&hv), __ATOMIC_RELAXED,
          __HIP_MEMORY_SCOPE_AGENT);
      asm volatile("s_waitcnt vmcnt(0)" ::: "memory");  // h acked at MALL
      // broadcast t+1 to 64 consumer mailboxes: ONE 64-lane scattered store
      __hip_atomic_store(mb + moff_prod, (unsigned)(t + 1), __ATOMIC_RELAXED,
                         __HIP_MEMORY_SCOPE_AGENT);
      if (t + 1 < Tn)  // xw prefetch hides under the next gate
        ad = *reinterpret_cast<const bf16x4*>(XW + xw_off + (long)(t + 1) * Hn);
    }

    // advance slots
    bf16_t* nn = hout;
    hout = rot ? (hout + Hstep) : hin;
    hin = nn;
  }

  // ---- V1 layer: z1 = relu(h_last @ V1^T + b1) for this group's 16 rows ----
  {
    // gate: my 8 producers have published h_Tn
    const unsigned tgt = (unsigned)Tn;
    for (;;) {
      unsigned v = __hip_atomic_load(mb + moff_cons, __ATOMIC_RELAXED,
                                     __HIP_MEMORY_SCOPE_AGENT);
      if (__all((int)(v >= tgt))) break;
    }
    asm volatile("" ::: "memory");
    if (!rot) __builtin_amdgcn_fence(__ATOMIC_ACQUIRE, "agent");

    const bf16_t* arow = hin + (long)(row0 + cl) * Hn + wv * 128 + kh * 8;
    f32x4 z[2] = {};
#pragma unroll
    for (int ksub = 0; ksub < 4; ++ksub) {
      bf16x8 a0 = *reinterpret_cast<const bf16x8*>(arow + ksub * 32);
#pragma unroll
      for (int ct = 0; ct < 2; ++ct) {
        const long voff = (long)(n0 + ct * 16 + cl) * Hn + wv * 128 + ksub * 32 + kh * 8;
        bf16x8 b0 = *reinterpret_cast<const bf16x8*>(V1w + voff);
        z[ct] = MFMA_16x16x32(a0, b0, z[ct]);
      }
    }
    float* red = redb;  // buffer 0: last written at t=510, reads done pre-sync511
#pragma unroll
    for (int ct = 0; ct < 2; ++ct)
#pragma unroll
      for (int q = 0; q < 4; ++q)
        red[wv * 512 + (kh * 4 + q) * 32 + ct * 16 + cl] = z[ct][q];
    __syncthreads();
    if (storer) {
      const int ri = srow * 32 + scol;
      float4 s = {0.f, 0.f, 0.f, 0.f};
#pragma unroll
      for (int w = 0; w < NW; ++w) {
        float4 p = *reinterpret_cast<const float4*>(&red[w * 512 + ri]);
        s.x += p.x; s.y += p.y; s.z += p.z; s.w += p.w;
      }
      float4 vb = *reinterpret_cast<const float4*>(V1b + n0 + scol);
      float4 o;
      o.x = fmaxf(s.x + vb.x, 0.f);
      o.y = fmaxf(s.y + vb.y, 0.f);
      o.z = fmaxf(s.z + vb.z, 0.f);
      o.w = fmaxf(s.w + vb.w, 0.f);
      *reinterpret_cast<float4*>(Z1 + (long)(row0 + srow) * Hn + n0 + scol) = o;
    }
  }

  // ---- FULL-grid barrier before head reads Z1 (release + acquire, once) ----
  {
    unsigned* fbar = slots + (size_t)NGRP * NGB * NW * 8;  // after mailboxes
    __syncthreads();
    if (tid == 0)
      __hip_atomic_store(fbar + (size_t)bid * 32, 1u,
                         __ATOMIC_RELEASE, __HIP_MEMORY_SCOPE_AGENT);
    if (tid < 64) {
      for (;;) {
        unsigned a = __hip_atomic_load(fbar + (size_t)tid * 32,
                                       __ATOMIC_RELAXED, __HIP_MEMORY_SCOPE_AGENT);
        unsigned b = __hip_atomic_load(fbar + (size_t)(tid + 64) * 32,
                                       __ATOMIC_RELAXED, __HIP_MEMORY_SCOPE_AGENT);
        unsigned c = __hip_atomic_load(fbar + (size_t)(tid + 128) * 32,
                                       __ATOMIC_RELAXED, __HIP_MEMORY_SCOPE_AGENT);
        unsigned d = __hip_atomic_load(fbar + (size_t)(tid + 192) * 32,
                                       __ATOMIC_RELAXED, __HIP_MEMORY_SCOPE_AGENT);
        if (__all((int)((a >= 1u) && (b >= 1u) && (c >= 1u) && (d >= 1u)))) break;
      }
      __builtin_amdgcn_fence(__ATOMIC_ACQUIRE, "agent");
    }
    __syncthreads();
  }

  // ---- head: z2 = relu(z1 @ V2^T + b2); out = log_softmax ----
  if (bid < Bn) {
    const int b = bid;
    float p[Cn] = {0.f, 0.f, 0.f, 0.f, 0.f};
    for (int jj = tid; jj < Hn; jj += 1024) {
      const float x = Z1[(long)b * Hn + jj];
#pragma unroll
      for (int c = 0; c < Cn; ++c) p[c] += x * V2w[(long)c * Hn + jj];
    }
#pragma unroll
    for (int c = 0; c < Cn; ++c)
      for (int off = 32; off; off >>= 1) p[c] += __shfl_down(p[c], off, 64);

    float* redh = reinterpret_cast<float*>(smem);
    if (lane == 0) {
#pragma unroll
      for (int c = 0; c < Cn; ++c) redh[c * NW + wv] = p[c];
    }
    __syncthreads();
    if (tid == 0) {
      float z[Cn];
      float mx = 0.f;
#pragma unroll
      for (int c = 0; c < Cn; ++c) {
        float s16 = 0.f;
#pragma unroll
        for (int w = 0; w < NW; ++w) s16 += redh[c * NW + w];
        z[c] = fmaxf(s16 + V2b[c], 0.f);
        mx = fmaxf(mx, z[c]);
      }
      float s = 0.f;
#pragma unroll
      for (int c = 0; c < Cn; ++c) s += expf(z[c] - mx);
      const float ls = logf(s);
#pragma unroll
      for (int c = 0; c < Cn; ++c) out[b * Cn + c] = z[c] - mx - ls;
    }
  }
}

// ---------------- host ----------------
extern "C" void kernel_launch(void* const* d_in, const int* in_sizes, int n_in,
                              void* d_out, int out_size, void* d_ws, size_t ws_size,
                              hipStream_t stream) {
  const float* inputs = (const float*)d_in[0];
  const float* W_w = (const float*)d_in[1];
  const float* W_b = (const float*)d_in[2];
  const float* U_w = (const float*)d_in[3];
  const float* U_b = (const float*)d_in[4];
  const float* V1_w = (const float*)d_in[5];
  const float* V1_b = (const float*)d_in[6];
  const float* V2_w = (const float*)d_in[7];
  const float* V2_b = (const float*)d_in[8];
  float* out = (float*)d_out;

  size_t off = 0;
  auto alloc = [&](size_t bytes) {
    void* p = (char*)d_ws + off;
    off += (bytes + 255) & ~(size_t)255;
    return p;
  };
  bf16_t* Wbf = (bf16_t*)alloc((size_t)Hn * Dn * 2);
  bf16_t* Uhi = (bf16_t*)alloc((size_t)Hn * Hn * 2);
  bf16_t* Ulo = (bf16_t*)alloc((size_t)Hn * Hn * 2);
  bf16_t* V1bf = (bf16_t*)alloc((size_t)Hn * Hn * 2);
  bf16_t* XW = (bf16_t*)alloc((size_t)Bn * Tn * Hn * 2);
  float* Z1 = (float*)alloc((size_t)Bn * Hn * 4);
  // mailboxes (NGRP*NGB*NW*8 u32 = 128 KB) + full-barrier (NBT*32 u32)
  const size_t slots_bytes = (size_t)(NGRP * NGB * NW * 8 + NBT * 32) * 4;
  unsigned* slots = (unsigned*)alloc(slots_bytes);

  // h chain: rotation if the workspace fits Tn+1 virgin slots, else ping-pong.
  const size_t slot_bytes = (size_t)Bn * Hn * 2;  // 256 KB
  const size_t rot_bytes = (size_t)(Tn + 1) * slot_bytes;
  const int rot = (ws_size - off) >= (rot_bytes + 256) ? 1 : 0;
  bf16_t* Hc = (bf16_t*)alloc(rot ? rot_bytes : 2 * slot_bytes);
  (void)ws_size;

  (void)hipFuncSetAttribute((const void*)scan_k,
                            hipFuncAttributeMaxDynamicSharedMemorySize, 65536);

  cvt_bf16_k<<<(Hn * Dn / 4 + 255) / 256, 256, 0, stream>>>(W_w, Wbf, Hn * Dn / 4);
  cvt_hilo_k<<<(Hn * Hn / 4 + 255) / 256, 256, 0, stream>>>(U_w, Uhi, Ulo, Hn * Hn / 4);
  cvt_bf16_k<<<(Hn * Hn / 4 + 255) / 256, 256, 0, stream>>>(V1_w, V1bf, Hn * Hn / 4);

  gemm_xw_k<<<dim3(Hn / 128, (Bn * Tn) / 128), 256, 0, stream>>>(inputs, Wbf, W_b, XW);

  (void)hipMemsetAsync(Hc, 0, slot_bytes, stream);  // slot 0 = h_0 = zeros
  (void)hipMemsetAsync(slots, 0, slots_bytes, stream);

  scan_k<<<NBT, 1024, 65536, stream>>>(Uhi, Ulo, U_b, XW, Hc, (long)Bn * Hn, rot,
                                       V1bf, V1_b, Z1, V2_w, V2_b, out, slots);
}

// Round 12
// 2668.034 us; speedup vs baseline: 1.2853x; 1.2853x over previous
//
#include <hip/hip_runtime.h>
#include <math.h>

typedef __bf16 bf16_t;
typedef __bf16 bf16x4 __attribute__((ext_vector_type(4)));
typedef __bf16 bf16x8 __attribute__((ext_vector_type(8)));
typedef float f32x4 __attribute__((ext_vector_type(4)));
typedef unsigned long long u64;

#define MFMA_16x16x32(A, B, C) __builtin_amdgcn_mfma_f32_16x16x32_bf16((A), (B), (C), 0, 0, 0)

static constexpr int Bn = 64;    // batch
static constexpr int Tn = 512;   // time
static constexpr int Dn = 1024;  // input dim
static constexpr int Hn = 2048;  // hidden
static constexpr int Cn = 5;     // classes
static constexpr int NGB = 64;   // blocks per batch-group
static constexpr int NGRP = 4;   // batch groups (16 rows each)
static constexpr int NBT = NGB * NGRP;  // 256 blocks = full GPU
static constexpr int NW = 16;    // waves per block (1024 threads)

// LDS swizzle for the xw GEMM tiles (32 bf16 = 64B rows)
#define SWZ64(row, kb)  ((((row) * 64) + (kb)) ^ (((row) & 3) << 4))

// ---------------- conversion kernels ----------------
__global__ __launch_bounds__(256) void cvt_bf16_k(const float* __restrict__ in,
                                                  bf16_t* __restrict__ out, int n4) {
  int i = blockIdx.x * 256 + threadIdx.x;
  if (i >= n4) return;
  float4 v = reinterpret_cast<const float4*>(in)[i];
  bf16x4 o;
  o[0] = (bf16_t)v.x; o[1] = (bf16_t)v.y; o[2] = (bf16_t)v.z; o[3] = (bf16_t)v.w;
  reinterpret_cast<bf16x4*>(out)[i] = o;
}

__global__ __launch_bounds__(256) void cvt_hilo_k(const float* __restrict__ in,
                                                  bf16_t* __restrict__ hi,
                                                  bf16_t* __restrict__ lo, int n4) {
  int i = blockIdx.x * 256 + threadIdx.x;
  if (i >= n4) return;
  float4 v = reinterpret_cast<const float4*>(in)[i];
  float f[4] = {v.x, v.y, v.z, v.w};
  bf16x4 h, l;
#pragma unroll
  for (int j = 0; j < 4; ++j) {
    bf16_t hb = (bf16_t)f[j];
    h[j] = hb;
    l[j] = (bf16_t)(f[j] - (float)hb);
  }
  reinterpret_cast<bf16x4*>(hi)[i] = h;
  reinterpret_cast<bf16x4*>(lo)[i] = l;
}

// ---------------- xw projection GEMM ----------------
__global__ __launch_bounds__(256) void gemm_xw_k(const float* __restrict__ A,
                                                 const bf16_t* __restrict__ Bw,
                                                 const float* __restrict__ bias,
                                                 bf16_t* __restrict__ C) {
  constexpr int K = Dn;
  constexpr int N = Hn;
  constexpr int NT = K / 32;
  __shared__ char As[2][128 * 64];
  __shared__ char Bs[2][128 * 64];

  const int tid = threadIdx.x;
  const int lane = tid & 63;
  const int wv = tid >> 6;
  const int wm = (wv >> 1) * 64;
  const int wn = (wv & 1) * 64;
  const int cl = lane & 15;
  const int kh = lane >> 4;
  const long m0 = (long)blockIdx.y * 128;
  const long n0 = (long)blockIdx.x * 128;

  const int srow = tid >> 1;
  const int scolb = (tid & 1) * 32;

  f32x4 acc[4][4] = {};
  float4 pa[4];
  uint4 pb[2];

  auto issue = [&](int kt) {
    const float* ap = A + (m0 + srow) * K + kt * 32 + (tid & 1) * 16;
#pragma unroll
    for (int i = 0; i < 4; ++i) pa[i] = reinterpret_cast<const float4*>(ap)[i];
    const bf16_t* bp = Bw + (n0 + srow) * K + kt * 32 + (tid & 1) * 16;
    pb[0] = reinterpret_cast<const uint4*>(bp)[0];
    pb[1] = reinterpret_cast<const uint4*>(bp)[1];
  };
  auto commit = [&](int buf) {
    bf16x8 a0, a1;
    a0[0] = (bf16_t)pa[0].x; a0[1] = (bf16_t)pa[0].y; a0[2] = (bf16_t)pa[0].z; a0[3] = (bf16_t)pa[0].w;
    a0[4] = (bf16_t)pa[1].x; a0[5] = (bf16_t)pa[1].y; a0[6] = (bf16_t)pa[1].z; a0[7] = (bf16_t)pa[1].w;
    a1[0] = (bf16_t)pa[2].x; a1[1] = (bf16_t)pa[2].y; a1[2] = (bf16_t)pa[2].z; a1[3] = (bf16_t)pa[2].w;
    a1[4] = (bf16_t)pa[3].x; a1[5] = (bf16_t)pa[3].y; a1[6] = (bf16_t)pa[3].z; a1[7] = (bf16_t)pa[3].w;
    *reinterpret_cast<bf16x8*>(&As[buf][SWZ64(srow, scolb)]) = a0;
    *reinterpret_cast<bf16x8*>(&As[buf][SWZ64(srow, scolb + 16)]) = a1;
    *reinterpret_cast<uint4*>(&Bs[buf][SWZ64(srow, scolb)]) = pb[0];
    *reinterpret_cast<uint4*>(&Bs[buf][SWZ64(srow, scolb + 16)]) = pb[1];
  };

  issue(0);
  commit(0);
  for (int kt = 0; kt < NT; ++kt) {
    const int buf = kt & 1;
    __syncthreads();
    if (kt + 1 < NT) issue(kt + 1);
    bf16x8 af[4], bfr[4];
#pragma unroll
    for (int i = 0; i < 4; ++i)
      af[i] = *reinterpret_cast<const bf16x8*>(&As[buf][SWZ64(wm + i * 16 + cl, kh * 16)]);
#pragma unroll
    for (int j = 0; j < 4; ++j)
      bfr[j] = *reinterpret_cast<const bf16x8*>(&Bs[buf][SWZ64(wn + j * 16 + cl, kh * 16)]);
#pragma unroll
    for (int i = 0; i < 4; ++i)
#pragma unroll
      for (int j = 0; j < 4; ++j)
        acc[i][j] = MFMA_16x16x32(af[i], bfr[j], acc[i][j]);
    if (kt + 1 < NT) commit((kt + 1) & 1);
  }

  const int rl4 = kh * 4;
#pragma unroll
  for (int j = 0; j < 4; ++j) {
    const long gcol = n0 + wn + j * 16 + cl;
    const float bv = bias[gcol];
#pragma unroll
    for (int i = 0; i < 4; ++i) {
      const long grow = m0 + wm + i * 16 + rl4;
#pragma unroll
      for (int q = 0; q < 4; ++q)
        C[(grow + q) * N + gcol] = (bf16_t)(acc[i][j][q] + bv);
    }
  }
}

// ---------------- persistent scan kernel ----------------
// Round-12: r10 (best-known, 2220us scan) + SINGLE-STORER/SINGLE-FLAG.
//   Geometry (r10): 256 blocks x 1024 threads; 4 groups x 16 batch rows;
//   64 blocks/group x 32 cols; 16 waves = 16 k-splits x 128 K; U in VGPRs;
//   LDS = double-buffered red only; groups on XCD pairs (bid%8 heuristic).
//   Sync protocol = r10 verbatim (proven in r6/r9/r10; r7/r8/r11 rewrites
//   all lost to MALL contention), except:
//     ONE storer wave (wv0) covers the whole 16x32 tile (2 rows/lane,
//     2 u64 stores, 32 float4 combine reads), drains once, writes ONE
//     flag per block. Group flags 128 -> 64 => wave0 poll is ONE load per
//     lane (was 2), shortening detect and halving poll traffic.
// Coherence (r3): h stores sc0sc1 -> MALL; h loads plain cached on virgin
// rotated slots (no fence). Fallback rot=0: ping-pong + acquire fence.
__global__ __launch_bounds__(1024, 1) void scan_k(
    const bf16_t* __restrict__ Uhi, const bf16_t* __restrict__ Ulo,
    const float* __restrict__ Ub, const bf16_t* __restrict__ XW,
    bf16_t* __restrict__ Hc, long Hstep, int rot,
    const bf16_t* __restrict__ V1w, const float* __restrict__ V1b,
    float* __restrict__ Z1,
    const float* __restrict__ V2w, const float* __restrict__ V2b,
    float* __restrict__ out, unsigned* __restrict__ slots) {
  extern __shared__ char smem[];
  float* redb = (float*)smem;  // red[2][16][512] f32 = 64 KB

  const int tid = threadIdx.x;
  const int lane = tid & 63;
  const int wv = tid >> 6;             // 0..15 = k-split (128 K each)
  const int cl = lane & 15;
  const int kh = lane >> 4;
  const int bid = blockIdx.x;
  // XCD-pair group mapping (assumes bid%8 = XCD round-robin; perf-only)
  const int g = (bid & 7) >> 1;              // group 0..3
  const int j = (bid >> 3) * 2 + (bid & 1);  // group-local block 0..63
  const int n0 = j * 32;               // owned 32 columns
  const int row0 = g * 16;             // group's 16 batch rows
  unsigned* gflags = slots + (size_t)g * (NGB * 32);  // 64 flags, 128B apart

  // ---- U fragments direct from global (one-time; loop-invariant) ----
  bf16x8 Ubh[2][4], Ubl[2][4];  // [col-tile][ksub] = 64 VGPRs
#pragma unroll
  for (int ct = 0; ct < 2; ++ct)
#pragma unroll
    for (int ksub = 0; ksub < 4; ++ksub) {
      const long uoff = (long)(n0 + ct * 16 + cl) * Hn + wv * 128 + ksub * 32 + kh * 8;
      Ubh[ct][ksub] = *reinterpret_cast<const bf16x8*>(Uhi + uoff);
      Ubl[ct][ksub] = *reinterpret_cast<const bf16x8*>(Ulo + uoff);
    }

  // single storer wave (wv0): each lane owns rows {lr, lr+8} x 4 cols
  const bool storer = (wv == 0);
  const int lr = lane >> 3;                      // 0..7
  const int scol = (lane & 7) * 4;               // col group of 4
  float4 bv4 = {0.f, 0.f, 0.f, 0.f};
  if (storer) bv4 = *reinterpret_cast<const float4*>(Ub + n0 + scol);
  const long xw_off0 = (long)(row0 + lr) * (Tn * Hn) + n0 + scol;
  const long xw_off1 = (long)(row0 + lr + 8) * (Tn * Hn) + n0 + scol;

  bf16x4 ad0 = {}, ad1 = {};
  if (storer) {
    ad0 = *reinterpret_cast<const bf16x4*>(XW + xw_off0);
    ad1 = *reinterpret_cast<const bf16x4*>(XW + xw_off1);
  }

  bf16_t* hin = Hc;            // slot 0 = zeros
  bf16_t* hout = Hc + Hstep;   // slot 1

  for (int t = 0; t < Tn; ++t) {
    const bf16_t* arow = hin + (long)(row0 + cl) * Hn + wv * 128 + kh * 8;

    bf16x8 a[4];
#pragma unroll
    for (int ksub = 0; ksub < 4; ++ksub)
      a[ksub] = *reinterpret_cast<const bf16x8*>(arow + ksub * 32);

    f32x4 acch[2] = {}, accl[2] = {};
#pragma unroll
    for (int ksub = 0; ksub < 4; ++ksub) {
      acch[0] = MFMA_16x16x32(a[ksub], Ubh[0][ksub], acch[0]);
      accl[0] = MFMA_16x16x32(a[ksub], Ubl[0][ksub], accl[0]);
      acch[1] = MFMA_16x16x32(a[ksub], Ubh[1][ksub], acch[1]);
      accl[1] = MFMA_16x16x32(a[ksub], Ubl[1][ksub], accl[1]);
    }

    // k-split partials -> red[t&1] (double-buffered: no pre-sync needed)
    float* red = redb + (t & 1) * 8192;
#pragma unroll
    for (int ct = 0; ct < 2; ++ct)
#pragma unroll
      for (int q = 0; q < 4; ++q)
        red[wv * 512 + (kh * 4 + q) * 32 + ct * 16 + cl] = acch[ct][q] + accl[ct][q];

    __syncthreads();  // sync B: all partials visible

    // storer wave: combine 16 k-splits for BOTH row halves, bias+xw+relu,
    // two u64 sc0sc1 stores, ONE wave-local drain, ONE flag.
    if (storer) {
      const int ri0 = lr * 32 + scol;
      const int ri1 = (lr + 8) * 32 + scol;
      float4 s0 = {0.f, 0.f, 0.f, 0.f}, s1 = {0.f, 0.f, 0.f, 0.f};
#pragma unroll
      for (int w = 0; w < NW; ++w) {
        float4 p0 = *reinterpret_cast<const float4*>(&red[w * 512 + ri0]);
        float4 p1 = *reinterpret_cast<const float4*>(&red[w * 512 + ri1]);
        s0.x += p0.x; s0.y += p0.y; s0.z += p0.z; s0.w += p0.w;
        s1.x += p1.x; s1.y += p1.y; s1.z += p1.z; s1.w += p1.w;
      }
      bf16x4 hv0, hv1;
      hv0[0] = (bf16_t)fmaxf(s0.x + bv4.x + (float)ad0[0], 0.f);
      hv0[1] = (bf16_t)fmaxf(s0.y + bv4.y + (float)ad0[1], 0.f);
      hv0[2] = (bf16_t)fmaxf(s0.z + bv4.z + (float)ad0[2], 0.f);
      hv0[3] = (bf16_t)fmaxf(s0.w + bv4.w + (float)ad0[3], 0.f);
      hv1[0] = (bf16_t)fmaxf(s1.x + bv4.x + (float)ad1[0], 0.f);
      hv1[1] = (bf16_t)fmaxf(s1.y + bv4.y + (float)ad1[1], 0.f);
      hv1[2] = (bf16_t)fmaxf(s1.z + bv4.z + (float)ad1[2], 0.f);
      hv1[3] = (bf16_t)fmaxf(s1.w + bv4.w + (float)ad1[3], 0.f);
      __hip_atomic_store(
          reinterpret_cast<u64*>(hout + (long)(row0 + lr) * Hn + n0 + scol),
          *reinterpret_cast<const u64*>(&hv0), __ATOMIC_RELAXED,
          __HIP_MEMORY_SCOPE_AGENT);
      __hip_atomic_store(
          reinterpret_cast<u64*>(hout + (long)(row0 + lr + 8) * Hn + n0 + scol),
          *reinterpret_cast<const u64*>(&hv1), __ATOMIC_RELAXED,
          __HIP_MEMORY_SCOPE_AGENT);
      asm volatile("s_waitcnt vmcnt(0)" ::: "memory");  // both acked at MALL
      if (lane == 0)
        __hip_atomic_store(gflags + (size_t)j * 32, (unsigned)(t + 1),
                           __ATOMIC_RELAXED, __HIP_MEMORY_SCOPE_AGENT);
      if (t + 1 < Tn) {  // xw prefetch hides under poll/sync
        ad0 = *reinterpret_cast<const bf16x4*>(XW + xw_off0 + (long)(t + 1) * Hn);
        ad1 = *reinterpret_cast<const bf16x4*>(XW + xw_off1 + (long)(t + 1) * Hn);
      }
    }

    const unsigned tgt = (unsigned)(t + 1);
    if (wv == 0) {  // wave 0 polls the group's 64 flags: ONE load per lane
      for (;;) {
        unsigned a0 = __hip_atomic_load(gflags + (size_t)lane * 32,
                                        __ATOMIC_RELAXED, __HIP_MEMORY_SCOPE_AGENT);
        if (__all((int)(a0 >= tgt))) break;
      }
      // rotation: no fence needed (virgin addresses can't be stale).
      if (!rot) __builtin_amdgcn_fence(__ATOMIC_ACQUIRE, "agent");
    }
    asm volatile("" ::: "memory");
    __syncthreads();  // sync D: release

    // advance slots
    bf16_t* nn = hout;
    hout = rot ? (hout + Hstep) : hin;
    hin = nn;
  }

  // ---- V1 layer: z1 = relu(h_last @ V1^T + b1) for this group's 16 rows ----
  {
    const bf16_t* arow = hin + (long)(row0 + cl) * Hn + wv * 128 + kh * 8;
    f32x4 z[2] = {};
#pragma unroll
    for (int ksub = 0; ksub < 4; ++ksub) {
      bf16x8 a0 = *reinterpret_cast<const bf16x8*>(arow + ksub * 32);
#pragma unroll
      for (int ct = 0; ct < 2; ++ct) {
        const long voff = (long)(n0 + ct * 16 + cl) * Hn + wv * 128 + ksub * 32 + kh * 8;
        bf16x8 b0 = *reinterpret_cast<const bf16x8*>(V1w + voff);
        z[ct] = MFMA_16x16x32(a0, b0, z[ct]);
      }
    }
    float* red = redb;  // buffer 0: last reader finished before final sync D
#pragma unroll
    for (int ct = 0; ct < 2; ++ct)
#pragma unroll
      for (int q = 0; q < 4; ++q)
        red[wv * 512 + (kh * 4 + q) * 32 + ct * 16 + cl] = z[ct][q];
    __syncthreads();
    if (storer) {
      const int ri0 = lr * 32 + scol;
      const int ri1 = (lr + 8) * 32 + scol;
      float4 s0 = {0.f, 0.f, 0.f, 0.f}, s1 = {0.f, 0.f, 0.f, 0.f};
#pragma unroll
      for (int w = 0; w < NW; ++w) {
        float4 p0 = *reinterpret_cast<const float4*>(&red[w * 512 + ri0]);
        float4 p1 = *reinterpret_cast<const float4*>(&red[w * 512 + ri1]);
        s0.x += p0.x; s0.y += p0.y; s0.z += p0.z; s0.w += p0.w;
        s1.x += p1.x; s1.y += p1.y; s1.z += p1.z; s1.w += p1.w;
      }
      float4 vb = *reinterpret_cast<const float4*>(V1b + n0 + scol);
      float4 o0, o1;
      o0.x = fmaxf(s0.x + vb.x, 0.f); o0.y = fmaxf(s0.y + vb.y, 0.f);
      o0.z = fmaxf(s0.z + vb.z, 0.f); o0.w = fmaxf(s0.w + vb.w, 0.f);
      o1.x = fmaxf(s1.x + vb.x, 0.f); o1.y = fmaxf(s1.y + vb.y, 0.f);
      o1.z = fmaxf(s1.z + vb.z, 0.f); o1.w = fmaxf(s1.w + vb.w, 0.f);
      *reinterpret_cast<float4*>(Z1 + (long)(row0 + lr) * Hn + n0 + scol) = o0;
      *reinterpret_cast<float4*>(Z1 + (long)(row0 + lr + 8) * Hn + n0 + scol) = o1;
    }
  }

  // ---- FULL-grid barrier before head reads Z1 (release + acquire, once) ----
  {
    unsigned* fbar = slots + (size_t)NGRP * NGB * 32;  // after group flags
    __syncthreads();
    if (tid == 0)
      __hip_atomic_store(fbar + (size_t)bid * 32, 1u,
                         __ATOMIC_RELEASE, __HIP_MEMORY_SCOPE_AGENT);
    if (tid < 64) {
      for (;;) {
        unsigned a = __hip_atomic_load(fbar + (size_t)tid * 32,
                                       __ATOMIC_RELAXED, __HIP_MEMORY_SCOPE_AGENT);
        unsigned b = __hip_atomic_load(fbar + (size_t)(tid + 64) * 32,
                                       __ATOMIC_RELAXED, __HIP_MEMORY_SCOPE_AGENT);
        unsigned c = __hip_atomic_load(fbar + (size_t)(tid + 128) * 32,
                                       __ATOMIC_RELAXED, __HIP_MEMORY_SCOPE_AGENT);
        unsigned d = __hip_atomic_load(fbar + (size_t)(tid + 192) * 32,
                                       __ATOMIC_RELAXED, __HIP_MEMORY_SCOPE_AGENT);
        if (__all((int)((a >= 1u) && (b >= 1u) && (c >= 1u) && (d >= 1u)))) break;
      }
      __builtin_amdgcn_fence(__ATOMIC_ACQUIRE, "agent");
    }
    __syncthreads();
  }

  // ---- head: z2 = relu(z1 @ V2^T + b2); out = log_softmax ----
  if (bid < Bn) {
    const int b = bid;
    float p[Cn] = {0.f, 0.f, 0.f, 0.f, 0.f};
    for (int jj = tid; jj < Hn; jj += 1024) {
      const float x = Z1[(long)b * Hn + jj];
#pragma unroll
      for (int c = 0; c < Cn; ++c) p[c] += x * V2w[(long)c * Hn + jj];
    }
#pragma unroll
    for (int c = 0; c < Cn; ++c)
      for (int off = 32; off; off >>= 1) p[c] += __shfl_down(p[c], off, 64);

    float* redh = reinterpret_cast<float*>(smem);
    if (lane == 0) {
#pragma unroll
      for (int c = 0; c < Cn; ++c) redh[c * NW + wv] = p[c];
    }
    __syncthreads();
    if (tid == 0) {
      float z[Cn];
      float mx = 0.f;
#pragma unroll
      for (int c = 0; c < Cn; ++c) {
        float s16 = 0.f;
#pragma unroll
        for (int w = 0; w < NW; ++w) s16 += redh[c * NW + w];
        z[c] = fmaxf(s16 + V2b[c], 0.f);
        mx = fmaxf(mx, z[c]);
      }
      float s = 0.f;
#pragma unroll
      for (int c = 0; c < Cn; ++c) s += expf(z[c] - mx);
      const float ls = logf(s);
#pragma unroll
      for (int c = 0; c < Cn; ++c) out[b * Cn + c] = z[c] - mx - ls;
    }
  }
}

// ---------------- host ----------------
extern "C" void kernel_launch(void* const* d_in, const int* in_sizes, int n_in,
                              void* d_out, int out_size, void* d_ws, size_t ws_size,
                              hipStream_t stream) {
  const float* inputs = (const float*)d_in[0];
  const float* W_w = (const float*)d_in[1];
  const float* W_b = (const float*)d_in[2];
  const float* U_w = (const float*)d_in[3];
  const float* U_b = (const float*)d_in[4];
  const float* V1_w = (const float*)d_in[5];
  const float* V1_b = (const float*)d_in[6];
  const float* V2_w = (const float*)d_in[7];
  const float* V2_b = (const float*)d_in[8];
  float* out = (float*)d_out;

  size_t off = 0;
  auto alloc = [&](size_t bytes) {
    void* p = (char*)d_ws + off;
    off += (bytes + 255) & ~(size_t)255;
    return p;
  };
  bf16_t* Wbf = (bf16_t*)alloc((size_t)Hn * Dn * 2);
  bf16_t* Uhi = (bf16_t*)alloc((size_t)Hn * Hn * 2);
  bf16_t* Ulo = (bf16_t*)alloc((size_t)Hn * Hn * 2);
  bf16_t* V1bf = (bf16_t*)alloc((size_t)Hn * Hn * 2);
  bf16_t* XW = (bf16_t*)alloc((size_t)Bn * Tn * Hn * 2);
  float* Z1 = (float*)alloc((size_t)Bn * Hn * 4);
  // group flags (NGRP*NGB slots, 128B each) + full-barrier (NBT, 128B each)
  const size_t slots_bytes = (size_t)(NGRP * NGB * 32 + NBT * 32) * 4;  // 64 KB
  unsigned* slots = (unsigned*)alloc(slots_bytes);

  // h chain: rotation if the workspace fits Tn+1 virgin slots, else ping-pong.
  const size_t slot_bytes = (size_t)Bn * Hn * 2;  // 256 KB
  const size_t rot_bytes = (size_t)(Tn + 1) * slot_bytes;
  const int rot = (ws_size - off) >= (rot_bytes + 256) ? 1 : 0;
  bf16_t* Hc = (bf16_t*)alloc(rot ? rot_bytes : 2 * slot_bytes);
  (void)ws_size;

  (void)hipFuncSetAttribute((const void*)scan_k,
                            hipFuncAttributeMaxDynamicSharedMemorySize, 65536);

  cvt_bf16_k<<<(Hn * Dn / 4 + 255) / 256, 256, 0, stream>>>(W_w, Wbf, Hn * Dn / 4);
  cvt_hilo_k<<<(Hn * Hn / 4 + 255) / 256, 256, 0, stream>>>(U_w, Uhi, Ulo, Hn * Hn / 4);
  cvt_bf16_k<<<(Hn * Hn / 4 + 255) / 256, 256, 0, stream>>>(V1_w, V1bf, Hn * Hn / 4);

  gemm_xw_k<<<dim3(Hn / 128, (Bn * Tn) / 128), 256, 0, stream>>>(inputs, Wbf, W_b, XW);

  (void)hipMemsetAsync(Hc, 0, slot_bytes, stream);  // slot 0 = h_0 = zeros
  (void)hipMemsetAsync(slots, 0, slots_bytes, stream);

  scan_k<<<NBT, 1024, 65536, stream>>>(Uhi, Ulo, U_b, XW, Hc, (long)Bn * Hn, rot,
                                       V1bf, V1_b, Z1, V2_w, V2_b, out, slots);
}

// Round 13
// 2616.855 us; speedup vs baseline: 1.3104x; 1.0196x over previous
//
#include <hip/hip_runtime.h>
#include <math.h>

typedef __bf16 bf16_t;
typedef __bf16 bf16x4 __attribute__((ext_vector_type(4)));
typedef __bf16 bf16x8 __attribute__((ext_vector_type(8)));
typedef float f32x4 __attribute__((ext_vector_type(4)));
typedef unsigned long long u64;

#define MFMA_16x16x32(A, B, C) __builtin_amdgcn_mfma_f32_16x16x32_bf16((A), (B), (C), 0, 0, 0)

static constexpr int Bn = 64;    // batch
static constexpr int Tn = 512;   // time
static constexpr int Dn = 1024;  // input dim
static constexpr int Hn = 2048;  // hidden
static constexpr int Cn = 5;     // classes
static constexpr int NGB = 64;   // blocks per batch-group
static constexpr int NGRP = 4;   // batch groups (16 rows each)
static constexpr int NBT = NGB * NGRP;  // 256 blocks = full GPU
static constexpr int NW = 16;    // waves per block (1024 threads)

// LDS swizzle for the xw GEMM tiles (32 bf16 = 64B rows)
#define SWZ64(row, kb)  ((((row) * 64) + (kb)) ^ (((row) & 3) << 4))

// ---------------- conversion kernels ----------------
__global__ __launch_bounds__(256) void cvt_bf16_k(const float* __restrict__ in,
                                                  bf16_t* __restrict__ out, int n4) {
  int i = blockIdx.x * 256 + threadIdx.x;
  if (i >= n4) return;
  float4 v = reinterpret_cast<const float4*>(in)[i];
  bf16x4 o;
  o[0] = (bf16_t)v.x; o[1] = (bf16_t)v.y; o[2] = (bf16_t)v.z; o[3] = (bf16_t)v.w;
  reinterpret_cast<bf16x4*>(out)[i] = o;
}

__global__ __launch_bounds__(256) void cvt_hilo_k(const float* __restrict__ in,
                                                  bf16_t* __restrict__ hi,
                                                  bf16_t* __restrict__ lo, int n4) {
  int i = blockIdx.x * 256 + threadIdx.x;
  if (i >= n4) return;
  float4 v = reinterpret_cast<const float4*>(in)[i];
  float f[4] = {v.x, v.y, v.z, v.w};
  bf16x4 h, l;
#pragma unroll
  for (int j = 0; j < 4; ++j) {
    bf16_t hb = (bf16_t)f[j];
    h[j] = hb;
    l[j] = (bf16_t)(f[j] - (float)hb);
  }
  reinterpret_cast<bf16x4*>(hi)[i] = h;
  reinterpret_cast<bf16x4*>(lo)[i] = l;
}

// ---------------- xw projection GEMM ----------------
__global__ __launch_bounds__(256) void gemm_xw_k(const float* __restrict__ A,
                                                 const bf16_t* __restrict__ Bw,
                                                 const float* __restrict__ bias,
                                                 bf16_t* __restrict__ C) {
  constexpr int K = Dn;
  constexpr int N = Hn;
  constexpr int NT = K / 32;
  __shared__ char As[2][128 * 64];
  __shared__ char Bs[2][128 * 64];

  const int tid = threadIdx.x;
  const int lane = tid & 63;
  const int wv = tid >> 6;
  const int wm = (wv >> 1) * 64;
  const int wn = (wv & 1) * 64;
  const int cl = lane & 15;
  const int kh = lane >> 4;
  const long m0 = (long)blockIdx.y * 128;
  const long n0 = (long)blockIdx.x * 128;

  const int srow = tid >> 1;
  const int scolb = (tid & 1) * 32;

  f32x4 acc[4][4] = {};
  float4 pa[4];
  uint4 pb[2];

  auto issue = [&](int kt) {
    const float* ap = A + (m0 + srow) * K + kt * 32 + (tid & 1) * 16;
#pragma unroll
    for (int i = 0; i < 4; ++i) pa[i] = reinterpret_cast<const float4*>(ap)[i];
    const bf16_t* bp = Bw + (n0 + srow) * K + kt * 32 + (tid & 1) * 16;
    pb[0] = reinterpret_cast<const uint4*>(bp)[0];
    pb[1] = reinterpret_cast<const uint4*>(bp)[1];
  };
  auto commit = [&](int buf) {
    bf16x8 a0, a1;
    a0[0] = (bf16_t)pa[0].x; a0[1] = (bf16_t)pa[0].y; a0[2] = (bf16_t)pa[0].z; a0[3] = (bf16_t)pa[0].w;
    a0[4] = (bf16_t)pa[1].x; a0[5] = (bf16_t)pa[1].y; a0[6] = (bf16_t)pa[1].z; a0[7] = (bf16_t)pa[1].w;
    a1[0] = (bf16_t)pa[2].x; a1[1] = (bf16_t)pa[2].y; a1[2] = (bf16_t)pa[2].z; a1[3] = (bf16_t)pa[2].w;
    a1[4] = (bf16_t)pa[3].x; a1[5] = (bf16_t)pa[3].y; a1[6] = (bf16_t)pa[3].z; a1[7] = (bf16_t)pa[3].w;
    *reinterpret_cast<bf16x8*>(&As[buf][SWZ64(srow, scolb)]) = a0;
    *reinterpret_cast<bf16x8*>(&As[buf][SWZ64(srow, scolb + 16)]) = a1;
    *reinterpret_cast<uint4*>(&Bs[buf][SWZ64(srow, scolb)]) = pb[0];
    *reinterpret_cast<uint4*>(&Bs[buf][SWZ64(srow, scolb + 16)]) = pb[1];
  };

  issue(0);
  commit(0);
  for (int kt = 0; kt < NT; ++kt) {
    const int buf = kt & 1;
    __syncthreads();
    if (kt + 1 < NT) issue(kt + 1);
    bf16x8 af[4], bfr[4];
#pragma unroll
    for (int i = 0; i < 4; ++i)
      af[i] = *reinterpret_cast<const bf16x8*>(&As[buf][SWZ64(wm + i * 16 + cl, kh * 16)]);
#pragma unroll
    for (int j = 0; j < 4; ++j)
      bfr[j] = *reinterpret_cast<const bf16x8*>(&Bs[buf][SWZ64(wn + j * 16 + cl, kh * 16)]);
#pragma unroll
    for (int i = 0; i < 4; ++i)
#pragma unroll
      for (int j = 0; j < 4; ++j)
        acc[i][j] = MFMA_16x16x32(af[i], bfr[j], acc[i][j]);
    if (kt + 1 < NT) commit((kt + 1) & 1);
  }

  const int rl4 = kh * 4;
#pragma unroll
  for (int j = 0; j < 4; ++j) {
    const long gcol = n0 + wn + j * 16 + cl;
    const float bv = bias[gcol];
#pragma unroll
    for (int i = 0; i < 4; ++i) {
      const long grow = m0 + wm + i * 16 + rl4;
#pragma unroll
      for (int q = 0; q < 4; ++q)
        C[(grow + q) * N + gcol] = (bf16_t)(acc[i][j][q] + bv);
    }
  }
}

// ---------------- persistent scan kernel ----------------
// Round-13: TRAFFIC-NEUTRAL TARGETED GATING on r12.
//   Geometry (r10/r12): 256 blocks x 1024 threads; 4 groups x 16 batch rows;
//   64 blocks/group x 32 cols; 16 waves = 16 k-splits x 128 K; U in VGPRs;
//   LDS = double-buffered red; single storer wave wv0, single flag/block.
//   Sync change: wave wv needs cols wv*128..+127 <- blocks 4wv..4wv+3 only.
//   Each wave polls ITS 4 producer flags (lanes duplicate over lane&3) at
//   loop top and self-gates; no wave0 relay, no post-poll __syncthreads.
//   TRAFFIC-NEUTRAL vs r12: per block per poll iter = 16 waves x 4 lines =
//   64 line-reads (r12: 1 wave x 64); per-line fan-in = 64 readers (same).
//   Zero new stores (r11's flood was the store broadcast; r7's was 4x read
//   traffic). Removes: relay MALL RT + syncD + max-over-64 jitter (now
//   max-over-4). 1 __syncthreads/step; red[2] parity proven in r11's
//   passing run (storer finishes red[p] reads before syncB_{t+1}, waves
//   rewrite red[p] only after syncB_{t+1}).
// Coherence (r3): h stores sc0sc1 -> MALL, acked (wave-local drain) before
// flag; h loads plain cached on virgin rotated slots (no fence). Fallback
// rot=0: ping-pong + per-wave acquire fence after each gate.
__global__ __launch_bounds__(1024, 1) void scan_k(
    const bf16_t* __restrict__ Uhi, const bf16_t* __restrict__ Ulo,
    const float* __restrict__ Ub, const bf16_t* __restrict__ XW,
    bf16_t* __restrict__ Hc, long Hstep, int rot,
    const bf16_t* __restrict__ V1w, const float* __restrict__ V1b,
    float* __restrict__ Z1,
    const float* __restrict__ V2w, const float* __restrict__ V2b,
    float* __restrict__ out, unsigned* __restrict__ slots) {
  extern __shared__ char smem[];
  float* redb = (float*)smem;  // red[2][16][512] f32 = 64 KB

  const int tid = threadIdx.x;
  const int lane = tid & 63;
  const int wv = tid >> 6;             // 0..15 = k-split (128 K each)
  const int cl = lane & 15;
  const int kh = lane >> 4;
  const int bid = blockIdx.x;
  // XCD-pair group mapping (assumes bid%8 = XCD round-robin; perf-only)
  const int g = (bid & 7) >> 1;              // group 0..3
  const int j = (bid >> 3) * 2 + (bid & 1);  // group-local block 0..63
  const int n0 = j * 32;               // owned 32 columns
  const int row0 = g * 16;             // group's 16 batch rows
  unsigned* gflags = slots + (size_t)g * (NGB * 32);  // 64 flags, 128B apart
  // targeted gate: my 4 producer flags (lanes duplicate over lane&3)
  const size_t fprod = (size_t)(4 * wv + (lane & 3)) * 32;

  // ---- U fragments direct from global (one-time; loop-invariant) ----
  bf16x8 Ubh[2][4], Ubl[2][4];  // [col-tile][ksub] = 64 VGPRs
#pragma unroll
  for (int ct = 0; ct < 2; ++ct)
#pragma unroll
    for (int ksub = 0; ksub < 4; ++ksub) {
      const long uoff = (long)(n0 + ct * 16 + cl) * Hn + wv * 128 + ksub * 32 + kh * 8;
      Ubh[ct][ksub] = *reinterpret_cast<const bf16x8*>(Uhi + uoff);
      Ubl[ct][ksub] = *reinterpret_cast<const bf16x8*>(Ulo + uoff);
    }

  // single storer wave (wv0): each lane owns rows {lr, lr+8} x 4 cols
  const bool storer = (wv == 0);
  const int lr = lane >> 3;                      // 0..7
  const int scol = (lane & 7) * 4;               // col group of 4
  float4 bv4 = {0.f, 0.f, 0.f, 0.f};
  if (storer) bv4 = *reinterpret_cast<const float4*>(Ub + n0 + scol);
  const long xw_off0 = (long)(row0 + lr) * (Tn * Hn) + n0 + scol;
  const long xw_off1 = (long)(row0 + lr + 8) * (Tn * Hn) + n0 + scol;

  bf16x4 ad0 = {}, ad1 = {};
  if (storer) {
    ad0 = *reinterpret_cast<const bf16x4*>(XW + xw_off0);
    ad1 = *reinterpret_cast<const bf16x4*>(XW + xw_off1);
  }

  bf16_t* hin = Hc;            // slot 0 = zeros
  bf16_t* hout = Hc + Hstep;   // slot 1

  for (int t = 0; t < Tn; ++t) {
    // ---- targeted self-gate: my 4 producers published h_t ----
    {
      const unsigned tgt = (unsigned)t;  // t=0: flags memset 0 -> passes
      for (;;) {
        unsigned v = __hip_atomic_load(gflags + fprod, __ATOMIC_RELAXED,
                                       __HIP_MEMORY_SCOPE_AGENT);
        if (__all((int)(v >= tgt))) break;
      }
      asm volatile("" ::: "memory");  // don't hoist h loads above the gate
      if (!rot) __builtin_amdgcn_fence(__ATOMIC_ACQUIRE, "agent");
    }

    const bf16_t* arow = hin + (long)(row0 + cl) * Hn + wv * 128 + kh * 8;

    bf16x8 a[4];
#pragma unroll
    for (int ksub = 0; ksub < 4; ++ksub)
      a[ksub] = *reinterpret_cast<const bf16x8*>(arow + ksub * 32);

    f32x4 acch[2] = {}, accl[2] = {};
#pragma unroll
    for (int ksub = 0; ksub < 4; ++ksub) {
      acch[0] = MFMA_16x16x32(a[ksub], Ubh[0][ksub], acch[0]);
      accl[0] = MFMA_16x16x32(a[ksub], Ubl[0][ksub], accl[0]);
      acch[1] = MFMA_16x16x32(a[ksub], Ubh[1][ksub], acch[1]);
      accl[1] = MFMA_16x16x32(a[ksub], Ubl[1][ksub], accl[1]);
    }

    // k-split partials -> red[t&1] (double-buffered)
    float* red = redb + (t & 1) * 8192;
#pragma unroll
    for (int ct = 0; ct < 2; ++ct)
#pragma unroll
      for (int q = 0; q < 4; ++q)
        red[wv * 512 + (kh * 4 + q) * 32 + ct * 16 + cl] = acch[ct][q] + accl[ct][q];

    __syncthreads();  // the ONLY block sync per step

    // storer wave: combine 16 k-splits for BOTH row halves, bias+xw+relu,
    // two u64 sc0sc1 stores, ONE wave-local drain, ONE flag.
    if (storer) {
      const int ri0 = lr * 32 + scol;
      const int ri1 = (lr + 8) * 32 + scol;
      float4 s0 = {0.f, 0.f, 0.f, 0.f}, s1 = {0.f, 0.f, 0.f, 0.f};
#pragma unroll
      for (int w = 0; w < NW; ++w) {
        float4 p0 = *reinterpret_cast<const float4*>(&red[w * 512 + ri0]);
        float4 p1 = *reinterpret_cast<const float4*>(&red[w * 512 + ri1]);
        s0.x += p0.x; s0.y += p0.y; s0.z += p0.z; s0.w += p0.w;
        s1.x += p1.x; s1.y += p1.y; s1.z += p1.z; s1.w += p1.w;
      }
      bf16x4 hv0, hv1;
      hv0[0] = (bf16_t)fmaxf(s0.x + bv4.x + (float)ad0[0], 0.f);
      hv0[1] = (bf16_t)fmaxf(s0.y + bv4.y + (float)ad0[1], 0.f);
      hv0[2] = (bf16_t)fmaxf(s0.z + bv4.z + (float)ad0[2], 0.f);
      hv0[3] = (bf16_t)fmaxf(s0.w + bv4.w + (float)ad0[3], 0.f);
      hv1[0] = (bf16_t)fmaxf(s1.x + bv4.x + (float)ad1[0], 0.f);
      hv1[1] = (bf16_t)fmaxf(s1.y + bv4.y + (float)ad1[1], 0.f);
      hv1[2] = (bf16_t)fmaxf(s1.z + bv4.z + (float)ad1[2], 0.f);
      hv1[3] = (bf16_t)fmaxf(s1.w + bv4.w + (float)ad1[3], 0.f);
      __hip_atomic_store(
          reinterpret_cast<u64*>(hout + (long)(row0 + lr) * Hn + n0 + scol),
          *reinterpret_cast<const u64*>(&hv0), __ATOMIC_RELAXED,
          __HIP_MEMORY_SCOPE_AGENT);
      __hip_atomic_store(
          reinterpret_cast<u64*>(hout + (long)(row0 + lr + 8) * Hn + n0 + scol),
          *reinterpret_cast<const u64*>(&hv1), __ATOMIC_RELAXED,
          __HIP_MEMORY_SCOPE_AGENT);
      asm volatile("s_waitcnt vmcnt(0)" ::: "memory");  // both acked at MALL
      if (lane == 0)
        __hip_atomic_store(gflags + (size_t)j * 32, (unsigned)(t + 1),
                           __ATOMIC_RELAXED, __HIP_MEMORY_SCOPE_AGENT);
      if (t + 1 < Tn) {  // xw prefetch hides under the next gate
        ad0 = *reinterpret_cast<const bf16x4*>(XW + xw_off0 + (long)(t + 1) * Hn);
        ad1 = *reinterpret_cast<const bf16x4*>(XW + xw_off1 + (long)(t + 1) * Hn);
      }
    }

    // advance slots
    bf16_t* nn = hout;
    hout = rot ? (hout + Hstep) : hin;
    hin = nn;
  }

  // ---- V1 layer: z1 = relu(h_last @ V1^T + b1) for this group's 16 rows ----
  {
    // targeted gate: my 4 producers published h_Tn
    const unsigned tgt = (unsigned)Tn;
    for (;;) {
      unsigned v = __hip_atomic_load(gflags + fprod, __ATOMIC_RELAXED,
                                     __HIP_MEMORY_SCOPE_AGENT);
      if (__all((int)(v >= tgt))) break;
    }
    asm volatile("" ::: "memory");
    if (!rot) __builtin_amdgcn_fence(__ATOMIC_ACQUIRE, "agent");

    const bf16_t* arow = hin + (long)(row0 + cl) * Hn + wv * 128 + kh * 8;
    f32x4 z[2] = {};
#pragma unroll
    for (int ksub = 0; ksub < 4; ++ksub) {
      bf16x8 a0 = *reinterpret_cast<const bf16x8*>(arow + ksub * 32);
#pragma unroll
      for (int ct = 0; ct < 2; ++ct) {
        const long voff = (long)(n0 + ct * 16 + cl) * Hn + wv * 128 + ksub * 32 + kh * 8;
        bf16x8 b0 = *reinterpret_cast<const bf16x8*>(V1w + voff);
        z[ct] = MFMA_16x16x32(a0, b0, z[ct]);
      }
    }
    float* red = redb;  // buffer 0: last reader finished before prior syncB
#pragma unroll
    for (int ct = 0; ct < 2; ++ct)
#pragma unroll
      for (int q = 0; q < 4; ++q)
        red[wv * 512 + (kh * 4 + q) * 32 + ct * 16 + cl] = z[ct][q];
    __syncthreads();
    if (storer) {
      const int ri0 = lr * 32 + scol;
      const int ri1 = (lr + 8) * 32 + scol;
      float4 s0 = {0.f, 0.f, 0.f, 0.f}, s1 = {0.f, 0.f, 0.f, 0.f};
#pragma unroll
      for (int w = 0; w < NW; ++w) {
        float4 p0 = *reinterpret_cast<const float4*>(&red[w * 512 + ri0]);
        float4 p1 = *reinterpret_cast<const float4*>(&red[w * 512 + ri1]);
        s0.x += p0.x; s0.y += p0.y; s0.z += p0.z; s0.w += p0.w;
        s1.x += p1.x; s1.y += p1.y; s1.z += p1.z; s1.w += p1.w;
      }
      float4 vb = *reinterpret_cast<const float4*>(V1b + n0 + scol);
      float4 o0, o1;
      o0.x = fmaxf(s0.x + vb.x, 0.f); o0.y = fmaxf(s0.y + vb.y, 0.f);
      o0.z = fmaxf(s0.z + vb.z, 0.f); o0.w = fmaxf(s0.w + vb.w, 0.f);
      o1.x = fmaxf(s1.x + vb.x, 0.f); o1.y = fmaxf(s1.y + vb.y, 0.f);
      o1.z = fmaxf(s1.z + vb.z, 0.f); o1.w = fmaxf(s1.w + vb.w, 0.f);
      *reinterpret_cast<float4*>(Z1 + (long)(row0 + lr) * Hn + n0 + scol) = o0;
      *reinterpret_cast<float4*>(Z1 + (long)(row0 + lr + 8) * Hn + n0 + scol) = o1;
    }
  }

  // ---- FULL-grid barrier before head reads Z1 (release + acquire, once) ----
  {
    unsigned* fbar = slots + (size_t)NGRP * NGB * 32;  // after group flags
    __syncthreads();
    if (tid == 0)
      __hip_atomic_store(fbar + (size_t)bid * 32, 1u,
                         __ATOMIC_RELEASE, __HIP_MEMORY_SCOPE_AGENT);
    if (tid < 64) {
      for (;;) {
        unsigned a = __hip_atomic_load(fbar + (size_t)tid * 32,
                                       __ATOMIC_RELAXED, __HIP_MEMORY_SCOPE_AGENT);
        unsigned b = __hip_atomic_load(fbar + (size_t)(tid + 64) * 32,
                                       __ATOMIC_RELAXED, __HIP_MEMORY_SCOPE_AGENT);
        unsigned c = __hip_atomic_load(fbar + (size_t)(tid + 128) * 32,
                                       __ATOMIC_RELAXED, __HIP_MEMORY_SCOPE_AGENT);
        unsigned d = __hip_atomic_load(fbar + (size_t)(tid + 192) * 32,
                                       __ATOMIC_RELAXED, __HIP_MEMORY_SCOPE_AGENT);
        if (__all((int)((a >= 1u) && (b >= 1u) && (c >= 1u) && (d >= 1u)))) break;
      }
      __builtin_amdgcn_fence(__ATOMIC_ACQUIRE, "agent");
    }
    __syncthreads();
  }

  // ---- head: z2 = relu(z1 @ V2^T + b2); out = log_softmax ----
  if (bid < Bn) {
    const int b = bid;
    float p[Cn] = {0.f, 0.f, 0.f, 0.f, 0.f};
    for (int jj = tid; jj < Hn; jj += 1024) {
      const float x = Z1[(long)b * Hn + jj];
#pragma unroll
      for (int c = 0; c < Cn; ++c) p[c] += x * V2w[(long)c * Hn + jj];
    }
#pragma unroll
    for (int c = 0; c < Cn; ++c)
      for (int off = 32; off; off >>= 1) p[c] += __shfl_down(p[c], off, 64);

    float* redh = reinterpret_cast<float*>(smem);
    if (lane == 0) {
#pragma unroll
      for (int c = 0; c < Cn; ++c) redh[c * NW + wv] = p[c];
    }
    __syncthreads();
    if (tid == 0) {
      float z[Cn];
      float mx = 0.f;
#pragma unroll
      for (int c = 0; c < Cn; ++c) {
        float s16 = 0.f;
#pragma unroll
        for (int w = 0; w < NW; ++w) s16 += redh[c * NW + w];
        z[c] = fmaxf(s16 + V2b[c], 0.f);
        mx = fmaxf(mx, z[c]);
      }
      float s = 0.f;
#pragma unroll
      for (int c = 0; c < Cn; ++c) s += expf(z[c] - mx);
      const float ls = logf(s);
#pragma unroll
      for (int c = 0; c < Cn; ++c) out[b * Cn + c] = z[c] - mx - ls;
    }
  }
}

// ---------------- host ----------------
extern "C" void kernel_launch(void* const* d_in, const int* in_sizes, int n_in,
                              void* d_out, int out_size, void* d_ws, size_t ws_size,
                              hipStream_t stream) {
  const float* inputs = (const float*)d_in[0];
  const float* W_w = (const float*)d_in[1];
  const float* W_b = (const float*)d_in[2];
  const float* U_w = (const float*)d_in[3];
  const float* U_b = (const float*)d_in[4];
  const float* V1_w = (const float*)d_in[5];
  const float* V1_b = (const float*)d_in[6];
  const float* V2_w = (const float*)d_in[7];
  const float* V2_b = (const float*)d_in[8];
  float* out = (float*)d_out;

  size_t off = 0;
  auto alloc = [&](size_t bytes) {
    void* p = (char*)d_ws + off;
    off += (bytes + 255) & ~(size_t)255;
    return p;
  };
  bf16_t* Wbf = (bf16_t*)alloc((size_t)Hn * Dn * 2);
  bf16_t* Uhi = (bf16_t*)alloc((size_t)Hn * Hn * 2);
  bf16_t* Ulo = (bf16_t*)alloc((size_t)Hn * Hn * 2);
  bf16_t* V1bf = (bf16_t*)alloc((size_t)Hn * Hn * 2);
  bf16_t* XW = (bf16_t*)alloc((size_t)Bn * Tn * Hn * 2);
  float* Z1 = (float*)alloc((size_t)Bn * Hn * 4);
  // group flags (NGRP*NGB slots, 128B each) + full-barrier (NBT, 128B each)
  const size_t slots_bytes = (size_t)(NGRP * NGB * 32 + NBT * 32) * 4;  // 64 KB
  unsigned* slots = (unsigned*)alloc(slots_bytes);

  // h chain: rotation if the workspace fits Tn+1 virgin slots, else ping-pong.
  const size_t slot_bytes = (size_t)Bn * Hn * 2;  // 256 KB
  const size_t rot_bytes = (size_t)(Tn + 1) * slot_bytes;
  const int rot = (ws_size - off) >= (rot_bytes + 256) ? 1 : 0;
  bf16_t* Hc = (bf16_t*)alloc(rot ? rot_bytes : 2 * slot_bytes);
  (void)ws_size;

  (void)hipFuncSetAttribute((const void*)scan_k,
                            hipFuncAttributeMaxDynamicSharedMemorySize, 65536);

  cvt_bf16_k<<<(Hn * Dn / 4 + 255) / 256, 256, 0, stream>>>(W_w, Wbf, Hn * Dn / 4);
  cvt_hilo_k<<<(Hn * Hn / 4 + 255) / 256, 256, 0, stream>>>(U_w, Uhi, Ulo, Hn * Hn / 4);
  cvt_bf16_k<<<(Hn * Hn / 4 + 255) / 256, 256, 0, stream>>>(V1_w, V1bf, Hn * Hn / 4);

  gemm_xw_k<<<dim3(Hn / 128, (Bn * Tn) / 128), 256, 0, stream>>>(inputs, Wbf, W_b, XW);

  (void)hipMemsetAsync(Hc, 0, slot_bytes, stream);  // slot 0 = h_0 = zeros
  (void)hipMemsetAsync(slots, 0, slots_bytes, stream);

  scan_k<<<NBT, 1024, 65536, stream>>>(Uhi, Ulo, U_b, XW, Hc, (long)Bn * Hn, rot,
                                       V1bf, V1_b, Z1, V2_w, V2_b, out, slots);
}

// Round 14
// 2414.506 us; speedup vs baseline: 1.4203x; 1.0838x over previous
//
#include <hip/hip_runtime.h>
#include <math.h>

typedef __bf16 bf16_t;
typedef __bf16 bf16x4 __attribute__((ext_vector_type(4)));
typedef __bf16 bf16x8 __attribute__((ext_vector_type(8)));
typedef float f32x4 __attribute__((ext_vector_type(4)));
typedef unsigned long long u64;

#define MFMA_16x16x32(A, B, C) __builtin_amdgcn_mfma_f32_16x16x32_bf16((A), (B), (C), 0, 0, 0)

static constexpr int Bn = 64;    // batch
static constexpr int Tn = 512;   // time
static constexpr int Dn = 1024;  // input dim
static constexpr int Hn = 2048;  // hidden
static constexpr int Cn = 5;     // classes
static constexpr int NGB = 64;   // blocks per batch-group
static constexpr int NGRP = 4;   // batch groups (16 rows each)
static constexpr int NBT = NGB * NGRP;  // 256 blocks = full GPU
static constexpr int NW = 16;    // waves per block (1024 threads)

// LDS swizzle for the legacy xw GEMM tiles (32 bf16 = 64B rows)
#define SWZ64(row, kb)  ((((row) * 64) + (kb)) ^ (((row) & 3) << 4))

// async global->LDS, 16B per lane (dest = wave-uniform base + lane*16)
__device__ __forceinline__ void gl_lds16(const void* g, void* l) {
  __builtin_amdgcn_global_load_lds(
      (const __attribute__((address_space(1))) unsigned int*)g,
      (__attribute__((address_space(3))) unsigned int*)l, 16, 0, 0);
}

// ---------------- conversion kernels ----------------
__global__ __launch_bounds__(256) void cvt_bf16_k(const float* __restrict__ in,
                                                  bf16_t* __restrict__ out, int n4) {
  int i = blockIdx.x * 256 + threadIdx.x;
  if (i >= n4) return;
  float4 v = reinterpret_cast<const float4*>(in)[i];
  bf16x4 o;
  o[0] = (bf16_t)v.x; o[1] = (bf16_t)v.y; o[2] = (bf16_t)v.z; o[3] = (bf16_t)v.w;
  reinterpret_cast<bf16x4*>(out)[i] = o;
}

__global__ __launch_bounds__(256) void cvt_hilo_k(const float* __restrict__ in,
                                                  bf16_t* __restrict__ hi,
                                                  bf16_t* __restrict__ lo, int n4) {
  int i = blockIdx.x * 256 + threadIdx.x;
  if (i >= n4) return;
  float4 v = reinterpret_cast<const float4*>(in)[i];
  float f[4] = {v.x, v.y, v.z, v.w};
  bf16x4 h, l;
#pragma unroll
  for (int j = 0; j < 4; ++j) {
    bf16_t hb = (bf16_t)f[j];
    h[j] = hb;
    l[j] = (bf16_t)(f[j] - (float)hb);
  }
  reinterpret_cast<bf16x4*>(hi)[i] = h;
  reinterpret_cast<bf16x4*>(lo)[i] = l;
}

// ---------------- xw projection GEMM (fast path: bf16 A + global_load_lds) ----
// m97-style structure: 128x128 tile, BK=32, linear LDS (no swizzle -- required
// by global_load_lds), double-buffered, 16B-wide async staging. A is
// pre-converted to bf16 (identical rounding to the legacy in-kernel cvt).
__global__ __launch_bounds__(256) void gemm_xw_lds_k(
    const bf16_t* __restrict__ A, const bf16_t* __restrict__ Bw,
    const float* __restrict__ bias, bf16_t* __restrict__ C) {
  constexpr int K = Dn;        // 1024
  constexpr int N = Hn;        // 2048
  constexpr int NT = K / 32;   // 32
  __shared__ bf16_t As[2][128 * 32];   // 8 KB per buf, linear [row][32]
  __shared__ bf16_t Bs[2][128 * 32];

  const int tid = threadIdx.x;
  const int lane = tid & 63;
  const int wv = tid >> 6;          // 0..3
  const int wm = (wv >> 1) * 64;
  const int wn = (wv & 1) * 64;
  const int cl = lane & 15;
  const int kh = lane >> 4;
  const long m0 = (long)blockIdx.y * 128;
  const long n0 = (long)blockIdx.x * 128;

  // staging: 8 chunks x 16 rows; wave wv covers chunks 2wv, 2wv+1.
  // lane l -> LDS byte chunk*1024 + l*16 -> row chunk*16 + (l>>2), col (l&3)*8.
  const int r0 = lane >> 2;
  const int ce = (lane & 3) * 8;

  auto stage = [&](int bufi, int kt) {
#pragma unroll
    for (int c = 0; c < 2; ++c) {
      const int ch = wv * 2 + c;
      const int row = ch * 16 + r0;
      gl_lds16(A + (m0 + row) * K + kt * 32 + ce, &As[bufi][ch * 512]);
      gl_lds16(Bw + (n0 + row) * K + kt * 32 + ce, &Bs[bufi][ch * 512]);
    }
  };

  f32x4 acc[4][4] = {};
  stage(0, 0);
  for (int kt = 0; kt < NT; ++kt) {
    const int buf = kt & 1;
    __syncthreads();               // drains vmcnt: staged buf complete
    if (kt + 1 < NT) stage(buf ^ 1, kt + 1);
    bf16x8 af[4], bfr[4];
#pragma unroll
    for (int i = 0; i < 4; ++i)
      af[i] = *reinterpret_cast<const bf16x8*>(
          &As[buf][(wm + i * 16 + cl) * 32 + kh * 8]);
#pragma unroll
    for (int j = 0; j < 4; ++j)
      bfr[j] = *reinterpret_cast<const bf16x8*>(
          &Bs[buf][(wn + j * 16 + cl) * 32 + kh * 8]);
#pragma unroll
    for (int i = 0; i < 4; ++i)
#pragma unroll
      for (int j = 0; j < 4; ++j)
        acc[i][j] = MFMA_16x16x32(af[i], bfr[j], acc[i][j]);
  }

  const int rl4 = kh * 4;
#pragma unroll
  for (int j = 0; j < 4; ++j) {
    const long gcol = n0 + wn + j * 16 + cl;
    const float bv = bias[gcol];
#pragma unroll
    for (int i = 0; i < 4; ++i) {
      const long grow = m0 + wm + i * 16 + rl4;
#pragma unroll
      for (int q = 0; q < 4; ++q)
        C[(grow + q) * N + gcol] = (bf16_t)(acc[i][j][q] + bv);
    }
  }
}

// ---------------- xw projection GEMM (legacy fallback: fp32 A staging) ------
__global__ __launch_bounds__(256) void gemm_xw_k(const float* __restrict__ A,
                                                 const bf16_t* __restrict__ Bw,
                                                 const float* __restrict__ bias,
                                                 bf16_t* __restrict__ C) {
  constexpr int K = Dn;
  constexpr int N = Hn;
  constexpr int NT = K / 32;
  __shared__ char As[2][128 * 64];
  __shared__ char Bs[2][128 * 64];

  const int tid = threadIdx.x;
  const int lane = tid & 63;
  const int wv = tid >> 6;
  const int wm = (wv >> 1) * 64;
  const int wn = (wv & 1) * 64;
  const int cl = lane & 15;
  const int kh = lane >> 4;
  const long m0 = (long)blockIdx.y * 128;
  const long n0 = (long)blockIdx.x * 128;

  const int srow = tid >> 1;
  const int scolb = (tid & 1) * 32;

  f32x4 acc[4][4] = {};
  float4 pa[4];
  uint4 pb[2];

  auto issue = [&](int kt) {
    const float* ap = A + (m0 + srow) * K + kt * 32 + (tid & 1) * 16;
#pragma unroll
    for (int i = 0; i < 4; ++i) pa[i] = reinterpret_cast<const float4*>(ap)[i];
    const bf16_t* bp = Bw + (n0 + srow) * K + kt * 32 + (tid & 1) * 16;
    pb[0] = reinterpret_cast<const uint4*>(bp)[0];
    pb[1] = reinterpret_cast<const uint4*>(bp)[1];
  };
  auto commit = [&](int buf) {
    bf16x8 a0, a1;
    a0[0] = (bf16_t)pa[0].x; a0[1] = (bf16_t)pa[0].y; a0[2] = (bf16_t)pa[0].z; a0[3] = (bf16_t)pa[0].w;
    a0[4] = (bf16_t)pa[1].x; a0[5] = (bf16_t)pa[1].y; a0[6] = (bf16_t)pa[1].z; a0[7] = (bf16_t)pa[1].w;
    a1[0] = (bf16_t)pa[2].x; a1[1] = (bf16_t)pa[2].y; a1[2] = (bf16_t)pa[2].z; a1[3] = (bf16_t)pa[2].w;
    a1[4] = (bf16_t)pa[3].x; a1[5] = (bf16_t)pa[3].y; a1[6] = (bf16_t)pa[3].z; a1[7] = (bf16_t)pa[3].w;
    *reinterpret_cast<bf16x8*>(&As[buf][SWZ64(srow, scolb)]) = a0;
    *reinterpret_cast<bf16x8*>(&As[buf][SWZ64(srow, scolb + 16)]) = a1;
    *reinterpret_cast<uint4*>(&Bs[buf][SWZ64(srow, scolb)]) = pb[0];
    *reinterpret_cast<uint4*>(&Bs[buf][SWZ64(srow, scolb + 16)]) = pb[1];
  };

  issue(0);
  commit(0);
  for (int kt = 0; kt < NT; ++kt) {
    const int buf = kt & 1;
    __syncthreads();
    if (kt + 1 < NT) issue(kt + 1);
    bf16x8 af[4], bfr[4];
#pragma unroll
    for (int i = 0; i < 4; ++i)
      af[i] = *reinterpret_cast<const bf16x8*>(&As[buf][SWZ64(wm + i * 16 + cl, kh * 16)]);
#pragma unroll
    for (int j = 0; j < 4; ++j)
      bfr[j] = *reinterpret_cast<const bf16x8*>(&Bs[buf][SWZ64(wn + j * 16 + cl, kh * 16)]);
#pragma unroll
    for (int i = 0; i < 4; ++i)
#pragma unroll
      for (int j = 0; j < 4; ++j)
        acc[i][j] = MFMA_16x16x32(af[i], bfr[j], acc[i][j]);
    if (kt + 1 < NT) commit((kt + 1) & 1);
  }

  const int rl4 = kh * 4;
#pragma unroll
  for (int j = 0; j < 4; ++j) {
    const long gcol = n0 + wn + j * 16 + cl;
    const float bv = bias[gcol];
#pragma unroll
    for (int i = 0; i < 4; ++i) {
      const long grow = m0 + wm + i * 16 + rl4;
#pragma unroll
      for (int q = 0; q < 4; ++q)
        C[(grow + q) * N + gcol] = (bf16_t)(acc[i][j][q] + bv);
    }
  }
}

// ---------------- persistent scan kernel (r13, UNCHANGED — at sync-family floor) ----
__global__ __launch_bounds__(1024, 1) void scan_k(
    const bf16_t* __restrict__ Uhi, const bf16_t* __restrict__ Ulo,
    const float* __restrict__ Ub, const bf16_t* __restrict__ XW,
    bf16_t* __restrict__ Hc, long Hstep, int rot,
    const bf16_t* __restrict__ V1w, const float* __restrict__ V1b,
    float* __restrict__ Z1,
    const float* __restrict__ V2w, const float* __restrict__ V2b,
    float* __restrict__ out, unsigned* __restrict__ slots) {
  extern __shared__ char smem[];
  float* redb = (float*)smem;  // red[2][16][512] f32 = 64 KB

  const int tid = threadIdx.x;
  const int lane = tid & 63;
  const int wv = tid >> 6;             // 0..15 = k-split (128 K each)
  const int cl = lane & 15;
  const int kh = lane >> 4;
  const int bid = blockIdx.x;
  // XCD-pair group mapping (assumes bid%8 = XCD round-robin; perf-only)
  const int g = (bid & 7) >> 1;              // group 0..3
  const int j = (bid >> 3) * 2 + (bid & 1);  // group-local block 0..63
  const int n0 = j * 32;               // owned 32 columns
  const int row0 = g * 16;             // group's 16 batch rows
  unsigned* gflags = slots + (size_t)g * (NGB * 32);  // 64 flags, 128B apart
  // targeted gate: my 4 producer flags (lanes duplicate over lane&3)
  const size_t fprod = (size_t)(4 * wv + (lane & 3)) * 32;

  // ---- U fragments direct from global (one-time; loop-invariant) ----
  bf16x8 Ubh[2][4], Ubl[2][4];  // [col-tile][ksub] = 64 VGPRs
#pragma unroll
  for (int ct = 0; ct < 2; ++ct)
#pragma unroll
    for (int ksub = 0; ksub < 4; ++ksub) {
      const long uoff = (long)(n0 + ct * 16 + cl) * Hn + wv * 128 + ksub * 32 + kh * 8;
      Ubh[ct][ksub] = *reinterpret_cast<const bf16x8*>(Uhi + uoff);
      Ubl[ct][ksub] = *reinterpret_cast<const bf16x8*>(Ulo + uoff);
    }

  // single storer wave (wv0): each lane owns rows {lr, lr+8} x 4 cols
  const bool storer = (wv == 0);
  const int lr = lane >> 3;                      // 0..7
  const int scol = (lane & 7) * 4;               // col group of 4
  float4 bv4 = {0.f, 0.f, 0.f, 0.f};
  if (storer) bv4 = *reinterpret_cast<const float4*>(Ub + n0 + scol);
  const long xw_off0 = (long)(row0 + lr) * (Tn * Hn) + n0 + scol;
  const long xw_off1 = (long)(row0 + lr + 8) * (Tn * Hn) + n0 + scol;

  bf16x4 ad0 = {}, ad1 = {};
  if (storer) {
    ad0 = *reinterpret_cast<const bf16x4*>(XW + xw_off0);
    ad1 = *reinterpret_cast<const bf16x4*>(XW + xw_off1);
  }

  bf16_t* hin = Hc;            // slot 0 = zeros
  bf16_t* hout = Hc + Hstep;   // slot 1

  for (int t = 0; t < Tn; ++t) {
    // ---- targeted self-gate: my 4 producers published h_t ----
    {
      const unsigned tgt = (unsigned)t;  // t=0: flags memset 0 -> passes
      for (;;) {
        unsigned v = __hip_atomic_load(gflags + fprod, __ATOMIC_RELAXED,
                                       __HIP_MEMORY_SCOPE_AGENT);
        if (__all((int)(v >= tgt))) break;
      }
      asm volatile("" ::: "memory");  // don't hoist h loads above the gate
      if (!rot) __builtin_amdgcn_fence(__ATOMIC_ACQUIRE, "agent");
    }

    const bf16_t* arow = hin + (long)(row0 + cl) * Hn + wv * 128 + kh * 8;

    bf16x8 a[4];
#pragma unroll
    for (int ksub = 0; ksub < 4; ++ksub)
      a[ksub] = *reinterpret_cast<const bf16x8*>(arow + ksub * 32);

    f32x4 acch[2] = {}, accl[2] = {};
#pragma unroll
    for (int ksub = 0; ksub < 4; ++ksub) {
      acch[0] = MFMA_16x16x32(a[ksub], Ubh[0][ksub], acch[0]);
      accl[0] = MFMA_16x16x32(a[ksub], Ubl[0][ksub], accl[0]);
      acch[1] = MFMA_16x16x32(a[ksub], Ubh[1][ksub], acch[1]);
      accl[1] = MFMA_16x16x32(a[ksub], Ubl[1][ksub], accl[1]);
    }

    // k-split partials -> red[t&1] (double-buffered)
    float* red = redb + (t & 1) * 8192;
#pragma unroll
    for (int ct = 0; ct < 2; ++ct)
#pragma unroll
      for (int q = 0; q < 4; ++q)
        red[wv * 512 + (kh * 4 + q) * 32 + ct * 16 + cl] = acch[ct][q] + accl[ct][q];

    __syncthreads();  // the ONLY block sync per step

    // storer wave: combine 16 k-splits for BOTH row halves, bias+xw+relu,
    // two u64 sc0sc1 stores, ONE wave-local drain, ONE flag.
    if (storer) {
      const int ri0 = lr * 32 + scol;
      const int ri1 = (lr + 8) * 32 + scol;
      float4 s0 = {0.f, 0.f, 0.f, 0.f}, s1 = {0.f, 0.f, 0.f, 0.f};
#pragma unroll
      for (int w = 0; w < NW; ++w) {
        float4 p0 = *reinterpret_cast<const float4*>(&red[w * 512 + ri0]);
        float4 p1 = *reinterpret_cast<const float4*>(&red[w * 512 + ri1]);
        s0.x += p0.x; s0.y += p0.y; s0.z += p0.z; s0.w += p0.w;
        s1.x += p1.x; s1.y += p1.y; s1.z += p1.z; s1.w += p1.w;
      }
      bf16x4 hv0, hv1;
      hv0[0] = (bf16_t)fmaxf(s0.x + bv4.x + (float)ad0[0], 0.f);
      hv0[1] = (bf16_t)fmaxf(s0.y + bv4.y + (float)ad0[1], 0.f);
      hv0[2] = (bf16_t)fmaxf(s0.z + bv4.z + (float)ad0[2], 0.f);
      hv0[3] = (bf16_t)fmaxf(s0.w + bv4.w + (float)ad0[3], 0.f);
      hv1[0] = (bf16_t)fmaxf(s1.x + bv4.x + (float)ad1[0], 0.f);
      hv1[1] = (bf16_t)fmaxf(s1.y + bv4.y + (float)ad1[1], 0.f);
      hv1[2] = (bf16_t)fmaxf(s1.z + bv4.z + (float)ad1[2], 0.f);
      hv1[3] = (bf16_t)fmaxf(s1.w + bv4.w + (float)ad1[3], 0.f);
      __hip_atomic_store(
          reinterpret_cast<u64*>(hout + (long)(row0 + lr) * Hn + n0 + scol),
          *reinterpret_cast<const u64*>(&hv0), __ATOMIC_RELAXED,
          __HIP_MEMORY_SCOPE_AGENT);
      __hip_atomic_store(
          reinterpret_cast<u64*>(hout + (long)(row0 + lr + 8) * Hn + n0 + scol),
          *reinterpret_cast<const u64*>(&hv1), __ATOMIC_RELAXED,
          __HIP_MEMORY_SCOPE_AGENT);
      asm volatile("s_waitcnt vmcnt(0)" ::: "memory");  // both acked at MALL
      if (lane == 0)
        __hip_atomic_store(gflags + (size_t)j * 32, (unsigned)(t + 1),
                           __ATOMIC_RELAXED, __HIP_MEMORY_SCOPE_AGENT);
      if (t + 1 < Tn) {  // xw prefetch hides under the next gate
        ad0 = *reinterpret_cast<const bf16x4*>(XW + xw_off0 + (long)(t + 1) * Hn);
        ad1 = *reinterpret_cast<const bf16x4*>(XW + xw_off1 + (long)(t + 1) * Hn);
      }
    }

    // advance slots
    bf16_t* nn = hout;
    hout = rot ? (hout + Hstep) : hin;
    hin = nn;
  }

  // ---- V1 layer: z1 = relu(h_last @ V1^T + b1) for this group's 16 rows ----
  {
    // targeted gate: my 4 producers published h_Tn
    const unsigned tgt = (unsigned)Tn;
    for (;;) {
      unsigned v = __hip_atomic_load(gflags + fprod, __ATOMIC_RELAXED,
                                     __HIP_MEMORY_SCOPE_AGENT);
      if (__all((int)(v >= tgt))) break;
    }
    asm volatile("" ::: "memory");
    if (!rot) __builtin_amdgcn_fence(__ATOMIC_ACQUIRE, "agent");

    const bf16_t* arow = hin + (long)(row0 + cl) * Hn + wv * 128 + kh * 8;
    f32x4 z[2] = {};
#pragma unroll
    for (int ksub = 0; ksub < 4; ++ksub) {
      bf16x8 a0 = *reinterpret_cast<const bf16x8*>(arow + ksub * 32);
#pragma unroll
      for (int ct = 0; ct < 2; ++ct) {
        const long voff = (long)(n0 + ct * 16 + cl) * Hn + wv * 128 + ksub * 32 + kh * 8;
        bf16x8 b0 = *reinterpret_cast<const bf16x8*>(V1w + voff);
        z[ct] = MFMA_16x16x32(a0, b0, z[ct]);
      }
    }
    float* red = redb;  // buffer 0: last reader finished before prior syncB
#pragma unroll
    for (int ct = 0; ct < 2; ++ct)
#pragma unroll
      for (int q = 0; q < 4; ++q)
        red[wv * 512 + (kh * 4 + q) * 32 + ct * 16 + cl] = z[ct][q];
    __syncthreads();
    if (storer) {
      const int ri0 = lr * 32 + scol;
      const int ri1 = (lr + 8) * 32 + scol;
      float4 s0 = {0.f, 0.f, 0.f, 0.f}, s1 = {0.f, 0.f, 0.f, 0.f};
#pragma unroll
      for (int w = 0; w < NW; ++w) {
        float4 p0 = *reinterpret_cast<const float4*>(&red[w * 512 + ri0]);
        float4 p1 = *reinterpret_cast<const float4*>(&red[w * 512 + ri1]);
        s0.x += p0.x; s0.y += p0.y; s0.z += p0.z; s0.w += p0.w;
        s1.x += p1.x; s1.y += p1.y; s1.z += p1.z; s1.w += p1.w;
      }
      float4 vb = *reinterpret_cast<const float4*>(V1b + n0 + scol);
      float4 o0, o1;
      o0.x = fmaxf(s0.x + vb.x, 0.f); o0.y = fmaxf(s0.y + vb.y, 0.f);
      o0.z = fmaxf(s0.z + vb.z, 0.f); o0.w = fmaxf(s0.w + vb.w, 0.f);
      o1.x = fmaxf(s1.x + vb.x, 0.f); o1.y = fmaxf(s1.y + vb.y, 0.f);
      o1.z = fmaxf(s1.z + vb.z, 0.f); o1.w = fmaxf(s1.w + vb.w, 0.f);
      *reinterpret_cast<float4*>(Z1 + (long)(row0 + lr) * Hn + n0 + scol) = o0;
      *reinterpret_cast<float4*>(Z1 + (long)(row0 + lr + 8) * Hn + n0 + scol) = o1;
    }
  }

  // ---- FULL-grid barrier before head reads Z1 (release + acquire, once) ----
  {
    unsigned* fbar = slots + (size_t)NGRP * NGB * 32;  // after group flags
    __syncthreads();
    if (tid == 0)
      __hip_atomic_store(fbar + (size_t)bid * 32, 1u,
                         __ATOMIC_RELEASE, __HIP_MEMORY_SCOPE_AGENT);
    if (tid < 64) {
      for (;;) {
        unsigned a = __hip_atomic_load(fbar + (size_t)tid * 32,
                                       __ATOMIC_RELAXED, __HIP_MEMORY_SCOPE_AGENT);
        unsigned b = __hip_atomic_load(fbar + (size_t)(tid + 64) * 32,
                                       __ATOMIC_RELAXED, __HIP_MEMORY_SCOPE_AGENT);
        unsigned c = __hip_atomic_load(fbar + (size_t)(tid + 128) * 32,
                                       __ATOMIC_RELAXED, __HIP_MEMORY_SCOPE_AGENT);
        unsigned d = __hip_atomic_load(fbar + (size_t)(tid + 192) * 32,
                                       __ATOMIC_RELAXED, __HIP_MEMORY_SCOPE_AGENT);
        if (__all((int)((a >= 1u) && (b >= 1u) && (c >= 1u) && (d >= 1u)))) break;
      }
      __builtin_amdgcn_fence(__ATOMIC_ACQUIRE, "agent");
    }
    __syncthreads();
  }

  // ---- head: z2 = relu(z1 @ V2^T + b2); out = log_softmax ----
  if (bid < Bn) {
    const int b = bid;
    float p[Cn] = {0.f, 0.f, 0.f, 0.f, 0.f};
    for (int jj = tid; jj < Hn; jj += 1024) {
      const float x = Z1[(long)b * Hn + jj];
#pragma unroll
      for (int c = 0; c < Cn; ++c) p[c] += x * V2w[(long)c * Hn + jj];
    }
#pragma unroll
    for (int c = 0; c < Cn; ++c)
      for (int off = 32; off; off >>= 1) p[c] += __shfl_down(p[c], off, 64);

    float* redh = reinterpret_cast<float*>(smem);
    if (lane == 0) {
#pragma unroll
      for (int c = 0; c < Cn; ++c) redh[c * NW + wv] = p[c];
    }
    __syncthreads();
    if (tid == 0) {
      float z[Cn];
      float mx = 0.f;
#pragma unroll
      for (int c = 0; c < Cn; ++c) {
        float s16 = 0.f;
#pragma unroll
        for (int w = 0; w < NW; ++w) s16 += redh[c * NW + w];
        z[c] = fmaxf(s16 + V2b[c], 0.f);
        mx = fmaxf(mx, z[c]);
      }
      float s = 0.f;
#pragma unroll
      for (int c = 0; c < Cn; ++c) s += expf(z[c] - mx);
      const float ls = logf(s);
#pragma unroll
      for (int c = 0; c < Cn; ++c) out[b * Cn + c] = z[c] - mx - ls;
    }
  }
}

// ---------------- host ----------------
extern "C" void kernel_launch(void* const* d_in, const int* in_sizes, int n_in,
                              void* d_out, int out_size, void* d_ws, size_t ws_size,
                              hipStream_t stream) {
  const float* inputs = (const float*)d_in[0];
  const float* W_w = (const float*)d_in[1];
  const float* W_b = (const float*)d_in[2];
  const float* U_w = (const float*)d_in[3];
  const float* U_b = (const float*)d_in[4];
  const float* V1_w = (const float*)d_in[5];
  const float* V1_b = (const float*)d_in[6];
  const float* V2_w = (const float*)d_in[7];
  const float* V2_b = (const float*)d_in[8];
  float* out = (float*)d_out;

  size_t off = 0;
  auto alloc = [&](size_t bytes) {
    void* p = (char*)d_ws + off;
    off += (bytes + 255) & ~(size_t)255;
    return p;
  };
  bf16_t* Wbf = (bf16_t*)alloc((size_t)Hn * Dn * 2);
  bf16_t* Uhi = (bf16_t*)alloc((size_t)Hn * Hn * 2);
  bf16_t* Ulo = (bf16_t*)alloc((size_t)Hn * Hn * 2);
  bf16_t* V1bf = (bf16_t*)alloc((size_t)Hn * Hn * 2);
  bf16_t* XW = (bf16_t*)alloc((size_t)Bn * Tn * Hn * 2);
  float* Z1 = (float*)alloc((size_t)Bn * Hn * 4);
  // group flags (NGRP*NGB slots, 128B each) + full-barrier (NBT, 128B each)
  const size_t slots_bytes = (size_t)(NGRP * NGB * 32 + NBT * 32) * 4;  // 64 KB
  unsigned* slots = (unsigned*)alloc(slots_bytes);

  // Optional bf16 copy of A for the fast gemm path; only if it fits ALONGSIDE
  // the rotation chain (scan's rot path is never sacrificed for the prologue).
  const size_t slot_bytes = (size_t)Bn * Hn * 2;  // 256 KB
  const size_t rot_bytes = (size_t)(Tn + 1) * slot_bytes;
  const size_t abf_bytes = (size_t)Bn * Tn * Dn * 2;  // 64 MB
  const int use_abf =
      (ws_size - off) >= (abf_bytes + 256 + rot_bytes + 256) ? 1 : 0;
  bf16_t* Abf = use_abf ? (bf16_t*)alloc(abf_bytes) : nullptr;

  // h chain: rotation if the workspace fits Tn+1 virgin slots, else ping-pong.
  const int rot = (ws_size - off) >= (rot_bytes + 256) ? 1 : 0;
  bf16_t* Hc = (bf16_t*)alloc(rot ? rot_bytes : 2 * slot_bytes);
  (void)ws_size;

  (void)hipFuncSetAttribute((const void*)scan_k,
                            hipFuncAttributeMaxDynamicSharedMemorySize, 65536);

  cvt_bf16_k<<<(Hn * Dn / 4 + 255) / 256, 256, 0, stream>>>(W_w, Wbf, Hn * Dn / 4);
  cvt_hilo_k<<<(Hn * Hn / 4 + 255) / 256, 256, 0, stream>>>(U_w, Uhi, Ulo, Hn * Hn / 4);
  cvt_bf16_k<<<(Hn * Hn / 4 + 255) / 256, 256, 0, stream>>>(V1_w, V1bf, Hn * Hn / 4);

  if (use_abf) {
    const int n4a = Bn * Tn * Dn / 4;
    cvt_bf16_k<<<(n4a + 255) / 256, 256, 0, stream>>>(inputs, Abf, n4a);
    gemm_xw_lds_k<<<dim3(Hn / 128, (Bn * Tn) / 128), 256, 0, stream>>>(
        Abf, Wbf, W_b, XW);
  } else {
    gemm_xw_k<<<dim3(Hn / 128, (Bn * Tn) / 128), 256, 0, stream>>>(
        inputs, Wbf, W_b, XW);
  }

  (void)hipMemsetAsync(Hc, 0, slot_bytes, stream);  // slot 0 = h_0 = zeros
  (void)hipMemsetAsync(slots, 0, slots_bytes, stream);

  scan_k<<<NBT, 1024, 65536, stream>>>(Uhi, Ulo, U_b, XW, Hc, (long)Bn * Hn, rot,
                                       V1bf, V1_b, Z1, V2_w, V2_b, out, slots);
}